// Round 1
// baseline (410.587 us; speedup 1.0000x reference)
//
#include <hip/hip_runtime.h>

#define NLON 512
#define NLAT 256
#define NC   64
#define NM   256           // truncated mmax (Nyquist bin m=256 is identically zero)
#define NL   256
#define RTOT (NC*NLAT)     // 16384 rows (c,k) — also 64*256 for (o,l)/(l,...) planes
#define PCT_MSTRIDE (NL*NLAT)

// ---- workspace layout (floats) ----
#define OFF_FRE 0
#define OFF_FIM (OFF_FRE + NLON*NM)      // 131072
#define OFF_GRE (OFF_FIM + NLON*NM)
#define OFF_GIM (OFF_GRE + NM*NLON)
#define OFF_WTR (OFF_GIM + NM*NLON)      // 524288
#define OFF_WTI (OFF_WTR + NL*NC*NC)     // +1048576
#define OFF_A_RE (OFF_WTI + NL*NC*NC)    // 2621440
#define OFF_A_IM (OFF_A_RE + NM*RTOT)
#define OFF_B_RE (OFF_A_IM + NM*RTOT)
#define OFF_B_IM (OFF_B_RE + NM*RTOT)
// total 19398656 floats = ~77.6 MB

__global__ void k_tables(float* __restrict__ Fre, float* __restrict__ Fim,
                         float* __restrict__ Gre, float* __restrict__ Gim) {
  int idx = blockIdx.x * blockDim.x + threadIdx.x;
  if (idx >= NLON * NM) return;
  const float step = 3.14159265358979323846f / 256.0f;
  {
    // F[n][m]: forward DFT, xf = (2*pi/512) * sum_n x[n] e^{-i 2pi n m/512}
    int n = idx / NM, m = idx % NM;
    int t = (n * m) & (NLON - 1);
    float th = t * step;
    const float sc = 6.2831853071795864769f / 512.0f;
    Fre[idx] = sc * cosf(th);
    Fim[idx] = -sc * sinf(th);
  }
  {
    // G[m][n]: inverse, y[n] = X0.re + 2*sum_{m>=1}(Xre cos - Xim sin); DC imag dropped (c2r)
    int m = idx / NLON, n = idx % NLON;
    int t = (m * n) & (NLON - 1);
    float th = t * step;
    float s = (m == 0) ? 1.0f : 2.0f;
    Gre[idx] = s * cosf(th);
    Gim[idx] = -s * sinf(th);
  }
}

// w [i][o][l] (64,64,256) -> wT [l][o][i]
__global__ void k_permw(const float* __restrict__ w, float* __restrict__ wT) {
  __shared__ float tile[32][33];
  int o = blockIdx.z;
  int i0 = blockIdx.y * 32;
  int l0 = blockIdx.x * 32;
  int xx = threadIdx.x, yy = threadIdx.y;
  for (int j = 0; j < 32; j += 8)
    tile[yy + j][xx] = w[(size_t)(i0 + yy + j) * (NC * NL) + (size_t)o * NL + l0 + xx];
  __syncthreads();
  for (int j = 0; j < 32; j += 8)
    wT[(size_t)(l0 + yy + j) * (NC * NC) + (size_t)o * NC + i0 + xx] = tile[xx][yy + j];
}

// src [A=256][64][B=256] -> dst [B][64][A]
__global__ void k_perm3(const float* __restrict__ src, float* __restrict__ dst) {
  __shared__ float tile[32][33];
  int a0 = blockIdx.x * 32, b0 = blockIdx.y * 32, c = blockIdx.z;
  int xx = threadIdx.x, yy = threadIdx.y;
  for (int j = 0; j < 32; j += 8)
    tile[yy + j][xx] = src[(size_t)(a0 + yy + j) * RTOT + (size_t)c * 256 + b0 + xx];
  __syncthreads();
  for (int j = 0; j < 32; j += 8)
    dst[(size_t)(b0 + yy + j) * RTOT + (size_t)c * 256 + a0 + xx] = tile[xx][yy + j];
}

// Stage 1: XF[m][r] (re,im) = sum_n x[r][n] * F[n][m], transposed store. r=(c,k)
__global__ __launch_bounds__(256) void k_dft_fwd(
    const float* __restrict__ x, const float* __restrict__ Fre,
    const float* __restrict__ Fim, float* __restrict__ XFre,
    float* __restrict__ XFim) {
  __shared__ float As[32][68];   // [k][r]
  __shared__ float Bre[32][68];  // [k][m]
  __shared__ float Bim[32][68];
  int t = threadIdx.x;
  int tx = t & 15, ty = t >> 4;  // tx -> r micro, ty -> m micro
  int r0 = blockIdx.x * 64, m0 = blockIdx.y * 64;
  float accr[4][4] = {}, acci[4][4] = {};
  for (int kk = 0; kk < NLON; kk += 32) {
    for (int rep = 0; rep < 2; ++rep) {
      int f = rep * 256 + t;
      int row = f >> 3, c4 = (f & 7) * 4;
      float4 v = *(const float4*)(x + (size_t)(r0 + row) * NLON + kk + c4);
      As[c4 + 0][row] = v.x; As[c4 + 1][row] = v.y;
      As[c4 + 2][row] = v.z; As[c4 + 3][row] = v.w;
      int rowb = f >> 4, c4b = (f & 15) * 4;
      *(float4*)&Bre[rowb][c4b] = *(const float4*)(Fre + (size_t)(kk + rowb) * NM + m0 + c4b);
      *(float4*)&Bim[rowb][c4b] = *(const float4*)(Fim + (size_t)(kk + rowb) * NM + m0 + c4b);
    }
    __syncthreads();
    for (int kl = 0; kl < 32; ++kl) {
      float4 a  = *(const float4*)&As[kl][tx * 4];
      float4 br = *(const float4*)&Bre[kl][ty * 4];
      float4 bi = *(const float4*)&Bim[kl][ty * 4];
      float av[4]  = {a.x, a.y, a.z, a.w};
      float brv[4] = {br.x, br.y, br.z, br.w};
      float biv[4] = {bi.x, bi.y, bi.z, bi.w};
      for (int i = 0; i < 4; ++i)
        for (int j = 0; j < 4; ++j) {
          accr[i][j] = fmaf(av[i], brv[j], accr[i][j]);
          acci[i][j] = fmaf(av[i], biv[j], acci[i][j]);
        }
    }
    __syncthreads();
  }
  for (int j = 0; j < 4; ++j) {
    float4 vr = {accr[0][j], accr[1][j], accr[2][j], accr[3][j]};
    float4 vi = {acci[0][j], acci[1][j], acci[2][j], acci[3][j]};
    size_t o = (size_t)(m0 + ty * 4 + j) * RTOT + r0 + tx * 4;
    *(float4*)(XFre + o) = vr;
    *(float4*)(XFim + o) = vi;
  }
}

// Stage 2 (per m): C[m][c][l] = sum_k XF[m][c][k] * shtw[m][l][k]
__global__ __launch_bounds__(256) void k_legendre_fwd(
    const float* __restrict__ XFre, const float* __restrict__ XFim,
    const float* __restrict__ shtw, float* __restrict__ Cre, float* __restrict__ Cim) {
  int m = blockIdx.y;
  int l0 = blockIdx.x * 64;
  int t = threadIdx.x;
  int tx = t & 15, ty = t >> 4;  // tx -> l micro, ty -> c micro
  size_t outbase = (size_t)m * RTOT;
  float4 zero = {0.f, 0.f, 0.f, 0.f};
  if (l0 + 64 <= m) {  // sub-diagonal: exactly zero
    for (int i = 0; i < 4; ++i) {
      size_t o = outbase + (size_t)(ty * 4 + i) * NL + l0 + tx * 4;
      *(float4*)(Cre + o) = zero;
      *(float4*)(Cim + o) = zero;
    }
    return;
  }
  __shared__ float Ar[32][68];  // [k][c]
  __shared__ float Ai[32][68];
  __shared__ float Bs[32][68];  // [k][l]
  const float* Agr = XFre + (size_t)m * RTOT;
  const float* Agi = XFim + (size_t)m * RTOT;
  const float* Bg  = shtw + (size_t)m * PCT_MSTRIDE;
  float accr[4][4] = {}, acci[4][4] = {};
  for (int kk = 0; kk < NLAT; kk += 32) {
    for (int rep = 0; rep < 2; ++rep) {
      int f = rep * 256 + t;
      int row = f >> 3, c4 = (f & 7) * 4;
      float4 vr = *(const float4*)(Agr + (size_t)row * NLAT + kk + c4);
      float4 vi = *(const float4*)(Agi + (size_t)row * NLAT + kk + c4);
      Ar[c4 + 0][row] = vr.x; Ar[c4 + 1][row] = vr.y; Ar[c4 + 2][row] = vr.z; Ar[c4 + 3][row] = vr.w;
      Ai[c4 + 0][row] = vi.x; Ai[c4 + 1][row] = vi.y; Ai[c4 + 2][row] = vi.z; Ai[c4 + 3][row] = vi.w;
      float4 vb = *(const float4*)(Bg + (size_t)(l0 + row) * NLAT + kk + c4);
      Bs[c4 + 0][row] = vb.x; Bs[c4 + 1][row] = vb.y; Bs[c4 + 2][row] = vb.z; Bs[c4 + 3][row] = vb.w;
    }
    __syncthreads();
    for (int kl = 0; kl < 32; ++kl) {
      float4 ar = *(const float4*)&Ar[kl][ty * 4];
      float4 ai = *(const float4*)&Ai[kl][ty * 4];
      float4 b  = *(const float4*)&Bs[kl][tx * 4];
      float arv[4] = {ar.x, ar.y, ar.z, ar.w};
      float aiv[4] = {ai.x, ai.y, ai.z, ai.w};
      float bv[4]  = {b.x, b.y, b.z, b.w};
      for (int i = 0; i < 4; ++i)
        for (int j = 0; j < 4; ++j) {
          accr[i][j] = fmaf(arv[i], bv[j], accr[i][j]);
          acci[i][j] = fmaf(aiv[i], bv[j], acci[i][j]);
        }
    }
    __syncthreads();
  }
  for (int i = 0; i < 4; ++i) {
    float4 vr = {accr[i][0], accr[i][1], accr[i][2], accr[i][3]};
    float4 vi = {acci[i][0], acci[i][1], acci[i][2], acci[i][3]};
    size_t o = outbase + (size_t)(ty * 4 + i) * NL + l0 + tx * 4;
    *(float4*)(Cre + o) = vr;
    *(float4*)(Cim + o) = vi;
  }
}

// Stage 3 (per l): O[l][o][m] = sum_i w[l][o][i] * CT[l][i][m]  (complex)
__global__ __launch_bounds__(256) void k_weight(
    const float* __restrict__ CTre, const float* __restrict__ CTim,
    const float* __restrict__ wTr, const float* __restrict__ wTi,
    float* __restrict__ Ore, float* __restrict__ Oim) {
  int l = blockIdx.y;
  int m0 = blockIdx.x * 64;
  int t = threadIdx.x;
  int ml = t & 63, og = t >> 6;
  size_t lbase = (size_t)l * RTOT;
  if (m0 > l) {  // coeffs zero for m > l
    for (int j = 0; j < 16; ++j) {
      int o = og * 16 + j;
      size_t off = lbase + (size_t)o * NM + m0 + ml;
      Ore[off] = 0.f; Oim[off] = 0.f;
    }
    return;
  }
  __shared__ float wr[4096], wi[4096];
  for (int rep = 0; rep < 4; ++rep) {
    int f = rep * 256 + t;
    ((float4*)wr)[f] = ((const float4*)(wTr + (size_t)l * 4096))[f];
    ((float4*)wi)[f] = ((const float4*)(wTi + (size_t)l * 4096))[f];
  }
  __syncthreads();
  float accr[16] = {}, acci[16] = {};
  for (int i = 0; i < 64; ++i) {
    float cr = CTre[lbase + (size_t)i * NM + m0 + ml];
    float ci = CTim[lbase + (size_t)i * NM + m0 + ml];
    for (int j = 0; j < 16; ++j) {
      int o = og * 16 + j;
      float wrv = wr[o * 64 + i];
      float wiv = wi[o * 64 + i];
      accr[j] = fmaf(wrv, cr, fmaf(-wiv, ci, accr[j]));
      acci[j] = fmaf(wrv, ci, fmaf(wiv, cr, acci[j]));
    }
  }
  for (int j = 0; j < 16; ++j) {
    int o = og * 16 + j;
    size_t off = lbase + (size_t)o * NM + m0 + ml;
    Ore[off] = accr[j];
    Oim[off] = acci[j];
  }
}

// Stage 4 (per m): XK[m][o][k] = sum_l OP[m][o][l] * pct[m][l][k]
__global__ __launch_bounds__(256) void k_legendre_inv(
    const float* __restrict__ Ore, const float* __restrict__ Oim,
    const float* __restrict__ pct, float* __restrict__ XKre, float* __restrict__ XKim) {
  int m = blockIdx.y;
  int k0 = blockIdx.x * 64;
  int t = threadIdx.x;
  int tx = t & 15, ty = t >> 4;  // tx -> k micro, ty -> o micro
  __shared__ float Ar[32][68];  // [l][o]
  __shared__ float Ai[32][68];
  __shared__ float Bs[32][68];  // [l][k]
  const float* Agr = Ore + (size_t)m * RTOT;
  const float* Agi = Oim + (size_t)m * RTOT;
  const float* Bg  = pct + (size_t)m * PCT_MSTRIDE;
  float accr[4][4] = {}, acci[4][4] = {};
  int lstart = m & ~31;  // pct[m][l<m]=0
  for (int ll0 = lstart; ll0 < NL; ll0 += 32) {
    for (int rep = 0; rep < 2; ++rep) {
      int f = rep * 256 + t;
      int row = f >> 3, c4 = (f & 7) * 4;
      float4 vr = *(const float4*)(Agr + (size_t)row * NL + ll0 + c4);
      float4 vi = *(const float4*)(Agi + (size_t)row * NL + ll0 + c4);
      Ar[c4 + 0][row] = vr.x; Ar[c4 + 1][row] = vr.y; Ar[c4 + 2][row] = vr.z; Ar[c4 + 3][row] = vr.w;
      Ai[c4 + 0][row] = vi.x; Ai[c4 + 1][row] = vi.y; Ai[c4 + 2][row] = vi.z; Ai[c4 + 3][row] = vi.w;
      int rowb = f >> 4, c4b = (f & 15) * 4;
      *(float4*)&Bs[rowb][c4b] = *(const float4*)(Bg + (size_t)(ll0 + rowb) * NLAT + k0 + c4b);
    }
    __syncthreads();
    for (int kl = 0; kl < 32; ++kl) {
      float4 ar = *(const float4*)&Ar[kl][ty * 4];
      float4 ai = *(const float4*)&Ai[kl][ty * 4];
      float4 b  = *(const float4*)&Bs[kl][tx * 4];
      float arv[4] = {ar.x, ar.y, ar.z, ar.w};
      float aiv[4] = {ai.x, ai.y, ai.z, ai.w};
      float bv[4]  = {b.x, b.y, b.z, b.w};
      for (int i = 0; i < 4; ++i)
        for (int j = 0; j < 4; ++j) {
          accr[i][j] = fmaf(arv[i], bv[j], accr[i][j]);
          acci[i][j] = fmaf(aiv[i], bv[j], acci[i][j]);
        }
    }
    __syncthreads();
  }
  for (int i = 0; i < 4; ++i) {
    float4 vr = {accr[i][0], accr[i][1], accr[i][2], accr[i][3]};
    float4 vi = {acci[i][0], acci[i][1], acci[i][2], acci[i][3]};
    size_t o = (size_t)m * RTOT + (size_t)(ty * 4 + i) * NLAT + k0 + tx * 4;
    *(float4*)(XKre + o) = vr;
    *(float4*)(XKim + o) = vi;
  }
}

// Stage 5: y[r][n] = sum_m XKre[m][r]*G_re[m][n] + XKim[m][r]*G_im[m][n]
__global__ __launch_bounds__(256) void k_dft_inv(
    const float* __restrict__ XKre, const float* __restrict__ XKim,
    const float* __restrict__ Gre, const float* __restrict__ Gim,
    float* __restrict__ y) {
  __shared__ float Ar[32][68];  // [m][r]
  __shared__ float Ai[32][68];
  __shared__ float Br[32][68];  // [m][n]
  __shared__ float Bi[32][68];
  int t = threadIdx.x;
  int tx = t & 15, ty = t >> 4;  // tx -> n micro, ty -> r micro
  int n0 = blockIdx.x * 64, r0 = blockIdx.y * 64;
  float acc[4][4] = {};
  for (int mk = 0; mk < NM; mk += 32) {
    for (int rep = 0; rep < 2; ++rep) {
      int f = rep * 256 + t;
      int row = f >> 4, c4 = (f & 15) * 4;
      *(float4*)&Ar[row][c4] = *(const float4*)(XKre + (size_t)(mk + row) * RTOT + r0 + c4);
      *(float4*)&Ai[row][c4] = *(const float4*)(XKim + (size_t)(mk + row) * RTOT + r0 + c4);
      *(float4*)&Br[row][c4] = *(const float4*)(Gre + (size_t)(mk + row) * NLON + n0 + c4);
      *(float4*)&Bi[row][c4] = *(const float4*)(Gim + (size_t)(mk + row) * NLON + n0 + c4);
    }
    __syncthreads();
    for (int mm = 0; mm < 32; ++mm) {
      float4 ar = *(const float4*)&Ar[mm][ty * 4];
      float4 ai = *(const float4*)&Ai[mm][ty * 4];
      float4 br = *(const float4*)&Br[mm][tx * 4];
      float4 bi = *(const float4*)&Bi[mm][tx * 4];
      float arv[4] = {ar.x, ar.y, ar.z, ar.w};
      float aiv[4] = {ai.x, ai.y, ai.z, ai.w};
      float brv[4] = {br.x, br.y, br.z, br.w};
      float biv[4] = {bi.x, bi.y, bi.z, bi.w};
      for (int i = 0; i < 4; ++i)
        for (int j = 0; j < 4; ++j) {
          acc[i][j] = fmaf(arv[i], brv[j], acc[i][j]);
          acc[i][j] = fmaf(aiv[i], biv[j], acc[i][j]);
        }
    }
    __syncthreads();
  }
  for (int i = 0; i < 4; ++i) {
    float4 v = {acc[i][0], acc[i][1], acc[i][2], acc[i][3]};
    *(float4*)(y + (size_t)(r0 + ty * 4 + i) * NLON + n0 + tx * 4) = v;
  }
}

extern "C" void kernel_launch(void* const* d_in, const int* in_sizes, int n_in,
                              void* d_out, int out_size, void* d_ws, size_t ws_size,
                              hipStream_t stream) {
  const float* x    = (const float*)d_in[0];
  const float* wgr  = (const float*)d_in[1];
  const float* wgi  = (const float*)d_in[2];
  const float* pct  = (const float*)d_in[3];
  const float* shtw = (const float*)d_in[4];
  float* out = (float*)d_out;
  float* ws  = (float*)d_ws;

  float* Fre = ws + OFF_FRE;
  float* Fim = ws + OFF_FIM;
  float* Gre = ws + OFF_GRE;
  float* Gim = ws + OFF_GIM;
  float* wTr = ws + OFF_WTR;
  float* wTi = ws + OFF_WTI;
  float* Are = ws + OFF_A_RE;
  float* Aim = ws + OFF_A_IM;
  float* Bre = ws + OFF_B_RE;
  float* Bim = ws + OFF_B_IM;

  hipLaunchKernelGGL(k_tables, dim3((NLON * NM + 255) / 256), dim3(256), 0, stream,
                     Fre, Fim, Gre, Gim);
  hipLaunchKernelGGL(k_permw, dim3(8, 2, 64), dim3(32, 8), 0, stream, wgr, wTr);
  hipLaunchKernelGGL(k_permw, dim3(8, 2, 64), dim3(32, 8), 0, stream, wgi, wTi);
  // Stage 1: XF[m][c*256+k] into A
  hipLaunchKernelGGL(k_dft_fwd, dim3(RTOT / 64, NM / 64), dim3(256), 0, stream,
                     x, Fre, Fim, Are, Aim);
  // Stage 2: coeffs [m][c][l] into B
  hipLaunchKernelGGL(k_legendre_fwd, dim3(NL / 64, NM), dim3(256), 0, stream,
                     Are, Aim, shtw, Bre, Bim);
  // Permute -> [l][c][m] into A
  hipLaunchKernelGGL(k_perm3, dim3(8, 8, 64), dim3(32, 8), 0, stream, Bre, Are);
  hipLaunchKernelGGL(k_perm3, dim3(8, 8, 64), dim3(32, 8), 0, stream, Bim, Aim);
  // Stage 3: weights -> [l][o][m] into B
  hipLaunchKernelGGL(k_weight, dim3(NM / 64, NL), dim3(256), 0, stream,
                     Are, Aim, wTr, wTi, Bre, Bim);
  // Permute -> [m][o][l] into A
  hipLaunchKernelGGL(k_perm3, dim3(8, 8, 64), dim3(32, 8), 0, stream, Bre, Are);
  hipLaunchKernelGGL(k_perm3, dim3(8, 8, 64), dim3(32, 8), 0, stream, Bim, Aim);
  // Stage 4: XK [m][o][k] into B
  hipLaunchKernelGGL(k_legendre_inv, dim3(NLAT / 64, NM), dim3(256), 0, stream,
                     Are, Aim, pct, Bre, Bim);
  // Stage 5: y
  hipLaunchKernelGGL(k_dft_inv, dim3(NLON / 64, RTOT / 64), dim3(256), 0, stream,
                     Bre, Bim, Gre, Gim, out);
  // Residual passthrough
  hipMemcpyAsync(out + (size_t)NC * NLAT * NLON, x,
                 sizeof(float) * NC * NLAT * NLON, hipMemcpyDeviceToDevice, stream);
}

// Round 2
// 187.043 us; speedup vs baseline: 2.1951x; 2.1951x over previous
//
#include <hip/hip_runtime.h>

typedef _Float16 f16;
typedef _Float16 h8 __attribute__((ext_vector_type(8)));
typedef float f4 __attribute__((ext_vector_type(4)));

#define NLON 512
#define NLAT 256
#define NC   64
#define NM   256
#define NL   256
#define RTOT (NC*NLAT)   // 16384

// ---- workspace byte offsets ----
#define BO_FTR 0
#define BO_FTI (BO_FTR + 262144)
#define BO_GR  (BO_FTI + 262144)
#define BO_GI  (BO_GR  + 262144)
#define BO_WTR (BO_GI  + 262144)          // f16 wT re  (2 MB)
#define BO_WTI (BO_WTR + 2097152)
#define BO_XFRE (BO_WTI + 2097152)        // f16 [m][r] (8 MB)  — also XK after S4
#define BO_XFIM (BO_XFRE + 8388608)
#define BO_CRE  (BO_XFIM + 8388608)       // f16 [m][c][l] — also W out, also XKT
#define BO_CIM  (BO_CRE + 8388608)
#define BO_PRE  (BO_CIM + 8388608)        // f16 perm buffer — also P2
#define BO_PIM  (BO_PRE + 8388608)
// end: 55574528 bytes (~53 MB)

__device__ inline f4 mfma16(h8 a, h8 b, f4 c) {
  return __builtin_amdgcn_mfma_f32_16x16x32_f16(a, b, c, 0, 0, 0);
}

// ---- tables: Ftr/Fti [m=256][n=512], Gr/Gi [n=512][m=256], all f16 ----
__global__ void k_tables_h(f16* __restrict__ Ftr, f16* __restrict__ Fti,
                           f16* __restrict__ Gr, f16* __restrict__ Gi) {
  int idx = blockIdx.x * blockDim.x + threadIdx.x;
  if (idx >= NLON * NM) return;
  const float step = 3.14159265358979323846f / 256.0f;
  {
    int m = idx >> 9, n = idx & 511;
    int t = (n * m) & (NLON - 1);
    float th = t * step;
    const float sc = 6.2831853071795864769f / 512.0f;
    Ftr[idx] = (f16)(sc * cosf(th));
    Fti[idx] = (f16)(-sc * sinf(th));
  }
  {
    int n = idx >> 8, m = idx & 255;
    int t = (n * m) & (NLON - 1);
    float th = t * step;
    float s = (m == 0) ? 1.0f : 2.0f;
    Gr[idx] = (f16)(s * cosf(th));
    Gi[idx] = (f16)(-s * sinf(th));
  }
}

// w [i][o][l] f32 -> wT [l][o][i] f16
__global__ void k_permw_h(const float* __restrict__ w, f16* __restrict__ wT) {
  __shared__ float tile[32][33];
  int o = blockIdx.z;
  int i0 = blockIdx.y * 32;
  int l0 = blockIdx.x * 32;
  int xx = threadIdx.x, yy = threadIdx.y;
  for (int j = 0; j < 32; j += 8)
    tile[yy + j][xx] = w[(size_t)(i0 + yy + j) * (NC * NL) + (size_t)o * NL + l0 + xx];
  __syncthreads();
  for (int j = 0; j < 32; j += 8)
    wT[(size_t)(l0 + yy + j) * (NC * NC) + (size_t)o * NC + i0 + xx] = (f16)tile[xx][yy + j];
}

// f16 3D permute: src [a=256][64][b=256] -> dst [b][64][a]
__global__ void k_perm3h(const f16* __restrict__ src, f16* __restrict__ dst) {
  __shared__ f16 tile[32][33];
  int a0 = blockIdx.x * 32, b0 = blockIdx.y * 32, c = blockIdx.z;
  int xx = threadIdx.x, yy = threadIdx.y;
  for (int j = 0; j < 32; j += 8)
    tile[yy + j][xx] = src[(size_t)(a0 + yy + j) * RTOT + (size_t)c * 256 + b0 + xx];
  __syncthreads();
  for (int j = 0; j < 32; j += 8)
    dst[(size_t)(b0 + yy + j) * RTOT + (size_t)c * 256 + a0 + xx] = tile[xx][yy + j];
}

// f16 2D transpose: src [256][16384] -> dst [16384][256]
__global__ void k_tr(const f16* __restrict__ src, f16* __restrict__ dst) {
  __shared__ f16 tile[32][33];
  int r0 = blockIdx.x * 32, m0 = blockIdx.y * 32;
  int xx = threadIdx.x, yy = threadIdx.y;
  for (int j = 0; j < 32; j += 8)
    tile[yy + j][xx] = src[(size_t)(m0 + yy + j) * RTOT + r0 + xx];
  __syncthreads();
  for (int j = 0; j < 32; j += 8)
    dst[(size_t)(r0 + yy + j) * 256 + m0 + xx] = tile[xx][yy + j];
}

// ---- S1: XF[m][r] = sum_n F[m][n] * x[r][n]  (re & im) ----
__global__ __launch_bounds__(256) void k_s1(
    const float* __restrict__ x, const f16* __restrict__ Ftr,
    const f16* __restrict__ Fti, f16* __restrict__ XFre, f16* __restrict__ XFim) {
  __shared__ f16 Ar[64][40], Ai[64][40], Bx[64][40];
  int t = threadIdx.x;
  int m0 = blockIdx.x * 64, r0 = blockIdx.y * 64;
  int lane = t & 63, w = t >> 6;
  int wm = (w >> 1) * 32, wn = (w & 1) * 32;
  int fr = lane & 15, kg = (lane >> 4) * 8;
  int srow = t >> 2, skc = (t & 3) * 8;
  f4 aR[2][2] = {}, aI[2][2] = {};
  for (int n0 = 0; n0 < NLON; n0 += 32) {
    *(h8*)&Ar[srow][skc] = *(const h8*)(Ftr + (size_t)(m0 + srow) * NLON + n0 + skc);
    *(h8*)&Ai[srow][skc] = *(const h8*)(Fti + (size_t)(m0 + srow) * NLON + n0 + skc);
    const float* px = x + (size_t)(r0 + srow) * NLON + n0 + skc;
    float4 v0 = *(const float4*)px;
    float4 v1 = *(const float4*)(px + 4);
    h8 hx = {(f16)v0.x, (f16)v0.y, (f16)v0.z, (f16)v0.w,
             (f16)v1.x, (f16)v1.y, (f16)v1.z, (f16)v1.w};
    *(h8*)&Bx[srow][skc] = hx;
    __syncthreads();
    h8 a0 = *(h8*)&Ar[wm + fr][kg],      a1 = *(h8*)&Ar[wm + 16 + fr][kg];
    h8 c0 = *(h8*)&Ai[wm + fr][kg],      c1 = *(h8*)&Ai[wm + 16 + fr][kg];
    h8 b0 = *(h8*)&Bx[wn + fr][kg],      b1 = *(h8*)&Bx[wn + 16 + fr][kg];
    aR[0][0] = mfma16(a0, b0, aR[0][0]); aR[0][1] = mfma16(a0, b1, aR[0][1]);
    aR[1][0] = mfma16(a1, b0, aR[1][0]); aR[1][1] = mfma16(a1, b1, aR[1][1]);
    aI[0][0] = mfma16(c0, b0, aI[0][0]); aI[0][1] = mfma16(c0, b1, aI[0][1]);
    aI[1][0] = mfma16(c1, b0, aI[1][0]); aI[1][1] = mfma16(c1, b1, aI[1][1]);
    __syncthreads();
  }
  int drow = (lane >> 4) * 4, dcol = lane & 15;
#pragma unroll
  for (int i = 0; i < 2; ++i)
#pragma unroll
    for (int j = 0; j < 2; ++j)
#pragma unroll
      for (int b = 0; b < 4; ++b) {
        size_t o = (size_t)(m0 + wm + i * 16 + drow + b) * RTOT + r0 + wn + j * 16 + dcol;
        XFre[o] = (f16)aR[i][j][b];
        XFim[o] = (f16)aI[i][j][b];
      }
}

// ---- S2 (per m): C[m][c][l] = sum_k XF[m][c][k] * shtw[m][l][k] ----
__global__ __launch_bounds__(256) void k_s2(
    const f16* __restrict__ XFre, const f16* __restrict__ XFim,
    const float* __restrict__ shtw, f16* __restrict__ Cre, f16* __restrict__ Cim) {
  int m = blockIdx.y;
  int l0 = blockIdx.x * 64;
  int t = threadIdx.x;
  if (l0 + 64 <= m) {  // exactly zero block
    int r = t >> 2, cc = (t & 3) * 16;
    h8 z = {};
    size_t o = (size_t)m * RTOT + (size_t)r * 256 + l0 + cc;
    *(h8*)&Cre[o] = z; *(h8*)&Cre[o + 8] = z;
    *(h8*)&Cim[o] = z; *(h8*)&Cim[o + 8] = z;
    return;
  }
  __shared__ f16 Ar[64][40], Ai[64][40], Bs[64][40];
  int lane = t & 63, w = t >> 6;
  int wm = (w >> 1) * 32, wn = (w & 1) * 32;
  int fr = lane & 15, kg = (lane >> 4) * 8;
  int srow = t >> 2, skc = (t & 3) * 8;
  const f16* Abr = XFre + (size_t)m * RTOT;
  const f16* Abi = XFim + (size_t)m * RTOT;
  const float* Bb = shtw + (size_t)m * (NL * NLAT);
  f4 aR[2][2] = {}, aI[2][2] = {};
  for (int k0 = 0; k0 < NLAT; k0 += 32) {
    *(h8*)&Ar[srow][skc] = *(const h8*)(Abr + (size_t)srow * NLAT + k0 + skc);
    *(h8*)&Ai[srow][skc] = *(const h8*)(Abi + (size_t)srow * NLAT + k0 + skc);
    const float* pb = Bb + (size_t)(l0 + srow) * NLAT + k0 + skc;
    float4 v0 = *(const float4*)pb;
    float4 v1 = *(const float4*)(pb + 4);
    h8 hb = {(f16)v0.x, (f16)v0.y, (f16)v0.z, (f16)v0.w,
             (f16)v1.x, (f16)v1.y, (f16)v1.z, (f16)v1.w};
    *(h8*)&Bs[srow][skc] = hb;
    __syncthreads();
    h8 a0 = *(h8*)&Ar[wm + fr][kg],      a1 = *(h8*)&Ar[wm + 16 + fr][kg];
    h8 c0 = *(h8*)&Ai[wm + fr][kg],      c1 = *(h8*)&Ai[wm + 16 + fr][kg];
    h8 b0 = *(h8*)&Bs[wn + fr][kg],      b1 = *(h8*)&Bs[wn + 16 + fr][kg];
    aR[0][0] = mfma16(a0, b0, aR[0][0]); aR[0][1] = mfma16(a0, b1, aR[0][1]);
    aR[1][0] = mfma16(a1, b0, aR[1][0]); aR[1][1] = mfma16(a1, b1, aR[1][1]);
    aI[0][0] = mfma16(c0, b0, aI[0][0]); aI[0][1] = mfma16(c0, b1, aI[0][1]);
    aI[1][0] = mfma16(c1, b0, aI[1][0]); aI[1][1] = mfma16(c1, b1, aI[1][1]);
    __syncthreads();
  }
  int drow = (lane >> 4) * 4, dcol = lane & 15;
#pragma unroll
  for (int i = 0; i < 2; ++i)
#pragma unroll
    for (int j = 0; j < 2; ++j)
#pragma unroll
      for (int b = 0; b < 4; ++b) {
        size_t o = (size_t)m * RTOT + (size_t)(wm + i * 16 + drow + b) * 256 + l0 + wn + j * 16 + dcol;
        Cre[o] = (f16)aR[i][j][b];
        Cim[o] = (f16)aI[i][j][b];
      }
}

// ---- S3 (per l): O[l][o][m] = sum_i w[l][o][i] * CT[l][i][m] (complex, fp32 VALU) ----
__global__ __launch_bounds__(256) void k_weight_h(
    const f16* __restrict__ CTre, const f16* __restrict__ CTim,
    const f16* __restrict__ wThr, const f16* __restrict__ wThi,
    f16* __restrict__ Ore, f16* __restrict__ Oim) {
  int l = blockIdx.y;
  int m0 = blockIdx.x * 64;
  int t = threadIdx.x;
  int ml = t & 63, og = t >> 6;
  size_t lbase = (size_t)l * RTOT;
  if (m0 > l) {
#pragma unroll
    for (int j = 0; j < 16; ++j) {
      int o = og * 16 + j;
      size_t off = lbase + (size_t)o * NM + m0 + ml;
      Ore[off] = (f16)0.f; Oim[off] = (f16)0.f;
    }
    return;
  }
  __shared__ float wr[4096], wi[4096];
  for (int rep = 0; rep < 16; ++rep) {
    int f = rep * 256 + t;
    wr[f] = (float)wThr[(size_t)l * 4096 + f];
    wi[f] = (float)wThi[(size_t)l * 4096 + f];
  }
  __syncthreads();
  float accr[16] = {}, acci[16] = {};
  for (int i = 0; i < 64; ++i) {
    float cr = (float)CTre[lbase + (size_t)i * NM + m0 + ml];
    float ci = (float)CTim[lbase + (size_t)i * NM + m0 + ml];
#pragma unroll
    for (int j = 0; j < 16; ++j) {
      int o = og * 16 + j;
      float wrv = wr[o * 64 + i];
      float wiv = wi[o * 64 + i];
      accr[j] = fmaf(wrv, cr, fmaf(-wiv, ci, accr[j]));
      acci[j] = fmaf(wrv, ci, fmaf(wiv, cr, acci[j]));
    }
  }
#pragma unroll
  for (int j = 0; j < 16; ++j) {
    int o = og * 16 + j;
    size_t off = lbase + (size_t)o * NM + m0 + ml;
    Ore[off] = (f16)accr[j];
    Oim[off] = (f16)acci[j];
  }
}

// ---- S4 (per m): XK[m][o][k] = sum_l O[m][o][l] * pct[m][l][k] ----
__global__ __launch_bounds__(256) void k_s4(
    const f16* __restrict__ Pre, const f16* __restrict__ Pim,
    const float* __restrict__ pct, f16* __restrict__ XKre, f16* __restrict__ XKim) {
  __shared__ f16 Ar[64][40], Ai[64][40], Bs[64][40];
  int m = blockIdx.y;
  int k0b = blockIdx.x * 64;
  int t = threadIdx.x;
  int lane = t & 63, w = t >> 6;
  int wm = (w >> 1) * 32, wn = (w & 1) * 32;
  int fr = lane & 15, kg = (lane >> 4) * 8;
  int srow = t >> 2, skc = (t & 3) * 8;
  int lrow = t >> 3, kcc = (t & 7) * 8;  // for transposed B staging
  const f16* Abr = Pre + (size_t)m * RTOT;
  const f16* Abi = Pim + (size_t)m * RTOT;
  const float* Bb = pct + (size_t)m * (NL * NLAT);
  f4 aR[2][2] = {}, aI[2][2] = {};
  int lstart = m & ~31;
  for (int l0 = lstart; l0 < NL; l0 += 32) {
    *(h8*)&Ar[srow][skc] = *(const h8*)(Abr + (size_t)srow * NL + l0 + skc);
    *(h8*)&Ai[srow][skc] = *(const h8*)(Abi + (size_t)srow * NL + l0 + skc);
    // B: pct[m][l][k] -> Bs[k - k0b][l - l0] (transpose in LDS)
    const float* pb = Bb + (size_t)(l0 + lrow) * NLAT + k0b + kcc;
    float4 v0 = *(const float4*)pb;
    float4 v1 = *(const float4*)(pb + 4);
    float vv[8] = {v0.x, v0.y, v0.z, v0.w, v1.x, v1.y, v1.z, v1.w};
#pragma unroll
    for (int e = 0; e < 8; ++e) Bs[kcc + e][lrow] = (f16)vv[e];
    __syncthreads();
    h8 a0 = *(h8*)&Ar[wm + fr][kg],      a1 = *(h8*)&Ar[wm + 16 + fr][kg];
    h8 c0 = *(h8*)&Ai[wm + fr][kg],      c1 = *(h8*)&Ai[wm + 16 + fr][kg];
    h8 b0 = *(h8*)&Bs[wn + fr][kg],      b1 = *(h8*)&Bs[wn + 16 + fr][kg];
    aR[0][0] = mfma16(a0, b0, aR[0][0]); aR[0][1] = mfma16(a0, b1, aR[0][1]);
    aR[1][0] = mfma16(a1, b0, aR[1][0]); aR[1][1] = mfma16(a1, b1, aR[1][1]);
    aI[0][0] = mfma16(c0, b0, aI[0][0]); aI[0][1] = mfma16(c0, b1, aI[0][1]);
    aI[1][0] = mfma16(c1, b0, aI[1][0]); aI[1][1] = mfma16(c1, b1, aI[1][1]);
    __syncthreads();
  }
  int drow = (lane >> 4) * 4, dcol = lane & 15;
#pragma unroll
  for (int i = 0; i < 2; ++i)
#pragma unroll
    for (int j = 0; j < 2; ++j)
#pragma unroll
      for (int b = 0; b < 4; ++b) {
        size_t o = (size_t)m * RTOT + (size_t)(wm + i * 16 + drow + b) * NLAT + k0b + wn + j * 16 + dcol;
        XKre[o] = (f16)aR[i][j][b];
        XKim[o] = (f16)aI[i][j][b];
      }
}

// ---- S5: y[r][n] = sum_m XKT[r][m]*Gr[n][m] + XKTim[r][m]*Gi[n][m] ----
__global__ __launch_bounds__(256) void k_s5(
    const f16* __restrict__ XKTre, const f16* __restrict__ XKTim,
    const f16* __restrict__ Gr, const f16* __restrict__ Gi,
    float* __restrict__ y) {
  __shared__ f16 Ar[64][40], Ai[64][40], Br[64][40], Bi[64][40];
  int t = threadIdx.x;
  int n0 = blockIdx.x * 64, r0 = blockIdx.y * 64;
  int lane = t & 63, w = t >> 6;
  int wm = (w >> 1) * 32, wn = (w & 1) * 32;
  int fr = lane & 15, kg = (lane >> 4) * 8;
  int srow = t >> 2, skc = (t & 3) * 8;
  f4 acc[2][2] = {};
  for (int m0 = 0; m0 < NM; m0 += 32) {
    *(h8*)&Ar[srow][skc] = *(const h8*)(XKTre + (size_t)(r0 + srow) * NM + m0 + skc);
    *(h8*)&Ai[srow][skc] = *(const h8*)(XKTim + (size_t)(r0 + srow) * NM + m0 + skc);
    *(h8*)&Br[srow][skc] = *(const h8*)(Gr + (size_t)(n0 + srow) * NM + m0 + skc);
    *(h8*)&Bi[srow][skc] = *(const h8*)(Gi + (size_t)(n0 + srow) * NM + m0 + skc);
    __syncthreads();
    h8 a0 = *(h8*)&Ar[wm + fr][kg], a1 = *(h8*)&Ar[wm + 16 + fr][kg];
    h8 c0 = *(h8*)&Ai[wm + fr][kg], c1 = *(h8*)&Ai[wm + 16 + fr][kg];
    h8 b0 = *(h8*)&Br[wn + fr][kg], b1 = *(h8*)&Br[wn + 16 + fr][kg];
    h8 d0 = *(h8*)&Bi[wn + fr][kg], d1 = *(h8*)&Bi[wn + 16 + fr][kg];
    acc[0][0] = mfma16(a0, b0, acc[0][0]); acc[0][1] = mfma16(a0, b1, acc[0][1]);
    acc[1][0] = mfma16(a1, b0, acc[1][0]); acc[1][1] = mfma16(a1, b1, acc[1][1]);
    acc[0][0] = mfma16(c0, d0, acc[0][0]); acc[0][1] = mfma16(c0, d1, acc[0][1]);
    acc[1][0] = mfma16(c1, d0, acc[1][0]); acc[1][1] = mfma16(c1, d1, acc[1][1]);
    __syncthreads();
  }
  int drow = (lane >> 4) * 4, dcol = lane & 15;
#pragma unroll
  for (int i = 0; i < 2; ++i)
#pragma unroll
    for (int j = 0; j < 2; ++j)
#pragma unroll
      for (int b = 0; b < 4; ++b)
        y[(size_t)(r0 + wm + i * 16 + drow + b) * NLON + n0 + wn + j * 16 + dcol] = acc[i][j][b];
}

extern "C" void kernel_launch(void* const* d_in, const int* in_sizes, int n_in,
                              void* d_out, int out_size, void* d_ws, size_t ws_size,
                              hipStream_t stream) {
  const float* x    = (const float*)d_in[0];
  const float* wgr  = (const float*)d_in[1];
  const float* wgi  = (const float*)d_in[2];
  const float* pct  = (const float*)d_in[3];
  const float* shtw = (const float*)d_in[4];
  float* out = (float*)d_out;
  char* ws = (char*)d_ws;

  f16* Ftr = (f16*)(ws + BO_FTR);
  f16* Fti = (f16*)(ws + BO_FTI);
  f16* Gr  = (f16*)(ws + BO_GR);
  f16* Gi  = (f16*)(ws + BO_GI);
  f16* wTr = (f16*)(ws + BO_WTR);
  f16* wTi = (f16*)(ws + BO_WTI);
  f16* XFre = (f16*)(ws + BO_XFRE);  // also XK region
  f16* XFim = (f16*)(ws + BO_XFIM);
  f16* Cre  = (f16*)(ws + BO_CRE);   // also W out, also XKT
  f16* Cim  = (f16*)(ws + BO_CIM);
  f16* Pre  = (f16*)(ws + BO_PRE);   // also P2
  f16* Pim  = (f16*)(ws + BO_PIM);

  hipLaunchKernelGGL(k_tables_h, dim3(512), dim3(256), 0, stream, Ftr, Fti, Gr, Gi);
  hipLaunchKernelGGL(k_permw_h, dim3(8, 2, 64), dim3(32, 8), 0, stream, wgr, wTr);
  hipLaunchKernelGGL(k_permw_h, dim3(8, 2, 64), dim3(32, 8), 0, stream, wgi, wTi);
  // S1: forward DFT -> XF[m][c][k] f16
  hipLaunchKernelGGL(k_s1, dim3(4, 256), dim3(256), 0, stream, x, Ftr, Fti, XFre, XFim);
  // S2: forward Legendre -> C[m][c][l] f16
  hipLaunchKernelGGL(k_s2, dim3(4, 256), dim3(256), 0, stream, XFre, XFim, shtw, Cre, Cim);
  // permute -> [l][c][m]
  hipLaunchKernelGGL(k_perm3h, dim3(8, 8, 64), dim3(32, 8), 0, stream, Cre, Pre);
  hipLaunchKernelGGL(k_perm3h, dim3(8, 8, 64), dim3(32, 8), 0, stream, Cim, Pim);
  // S3: weights -> [l][o][m] into C region
  hipLaunchKernelGGL(k_weight_h, dim3(4, 256), dim3(256), 0, stream, Pre, Pim, wTr, wTi, Cre, Cim);
  // permute -> [m][o][l] into P region
  hipLaunchKernelGGL(k_perm3h, dim3(8, 8, 64), dim3(32, 8), 0, stream, Cre, Pre);
  hipLaunchKernelGGL(k_perm3h, dim3(8, 8, 64), dim3(32, 8), 0, stream, Cim, Pim);
  // S4: inverse Legendre -> XK[m][o][k] f16 into XF region
  hipLaunchKernelGGL(k_s4, dim3(4, 256), dim3(256), 0, stream, Pre, Pim, pct, XFre, XFim);
  // transpose -> XKT[r][m] into C region
  hipLaunchKernelGGL(k_tr, dim3(512, 8), dim3(32, 8), 0, stream, XFre, Cre);
  hipLaunchKernelGGL(k_tr, dim3(512, 8), dim3(32, 8), 0, stream, XFim, Cim);
  // S5: inverse DFT -> y
  hipLaunchKernelGGL(k_s5, dim3(8, 256), dim3(256), 0, stream, Cre, Cim, Gr, Gi, out);
  // residual passthrough
  hipMemcpyAsync(out + (size_t)NC * NLAT * NLON, x,
                 sizeof(float) * NC * NLAT * NLON, hipMemcpyDeviceToDevice, stream);
}

// Round 3
// 148.423 us; speedup vs baseline: 2.7663x; 1.2602x over previous
//
#include <hip/hip_runtime.h>

typedef _Float16 f16;
typedef _Float16 h8 __attribute__((ext_vector_type(8)));
typedef float f4 __attribute__((ext_vector_type(4)));

#define NLON 512
#define NLAT 256
#define NC   64
#define NM   256
#define NL   256
#define RTOT (NC*NLAT)   // 16384

// ---- workspace byte offsets ----
#define BO_FTR 0
#define BO_FTI (BO_FTR + 262144)
#define BO_GR  (BO_FTI + 262144)
#define BO_GI  (BO_GR  + 262144)
#define BO_WTR (BO_GI  + 262144)
#define BO_WTI (BO_WTR + 2097152)
#define BO_XFRE (BO_WTI + 2097152)   // f16 [m][c][k] — reused as XK [m][o][k]
#define BO_XFIM (BO_XFRE + 8388608)
#define BO_PRE  (BO_XFIM + 8388608)  // f16 P [l][m][c]
#define BO_PIM  (BO_PRE + 8388608)
#define BO_QRE  (BO_PIM + 8388608)   // f16 Q [l][m][o]
#define BO_QIM  (BO_QRE + 8388608)
// end: 55574528 bytes (~53 MB)

__device__ inline f4 mfma16(h8 a, h8 b, f4 c) {
  return __builtin_amdgcn_mfma_f32_16x16x32_f16(a, b, c, 0, 0, 0);
}

// ---- tables: Ftr/Fti [m=256][n=512], Gr/Gi [n=512][m=256], all f16 ----
__global__ void k_tables_h(f16* __restrict__ Ftr, f16* __restrict__ Fti,
                           f16* __restrict__ Gr, f16* __restrict__ Gi) {
  int idx = blockIdx.x * blockDim.x + threadIdx.x;
  if (idx >= NLON * NM) return;
  const float step = 3.14159265358979323846f / 256.0f;
  {
    int m = idx >> 9, n = idx & 511;
    int t = (n * m) & (NLON - 1);
    float th = t * step;
    const float sc = 6.2831853071795864769f / 512.0f;
    Ftr[idx] = (f16)(sc * cosf(th));
    Fti[idx] = (f16)(-sc * sinf(th));
  }
  {
    int n = idx >> 8, m = idx & 255;
    int t = (n * m) & (NLON - 1);
    float th = t * step;
    float s = (m == 0) ? 1.0f : 2.0f;
    Gr[idx] = (f16)(s * cosf(th));
    Gi[idx] = (f16)(-s * sinf(th));
  }
}

// w [i][o][l] f32 -> wT [l][o][i] f16
__global__ void k_permw_h(const float* __restrict__ w, f16* __restrict__ wT) {
  __shared__ float tile[32][33];
  int o = blockIdx.z;
  int i0 = blockIdx.y * 32;
  int l0 = blockIdx.x * 32;
  int xx = threadIdx.x, yy = threadIdx.y;
  for (int j = 0; j < 32; j += 8)
    tile[yy + j][xx] = w[(size_t)(i0 + yy + j) * (NC * NL) + (size_t)o * NL + l0 + xx];
  __syncthreads();
  for (int j = 0; j < 32; j += 8)
    wT[(size_t)(l0 + yy + j) * (NC * NC) + (size_t)o * NC + i0 + xx] = (f16)tile[xx][yy + j];
}

// ---- S1: XF[m][c][k] = sum_n F[m][n] * x[(c,k)][n] ----
__global__ __launch_bounds__(256) void k_s1(
    const float* __restrict__ x, const f16* __restrict__ Ftr,
    const f16* __restrict__ Fti, f16* __restrict__ XFre, f16* __restrict__ XFim) {
  __shared__ f16 Ar[64][40], Ai[64][40], Bx[64][40];
  int t = threadIdx.x;
  int m0 = blockIdx.x * 64, r0 = blockIdx.y * 64;
  int lane = t & 63, w = t >> 6;
  int wm = (w >> 1) * 32, wn = (w & 1) * 32;
  int fr = lane & 15, kg = (lane >> 4) * 8;
  int srow = t >> 2, skc = (t & 3) * 8;
  f4 aR[2][2] = {}, aI[2][2] = {};
  for (int n0 = 0; n0 < NLON; n0 += 32) {
    *(h8*)&Ar[srow][skc] = *(const h8*)(Ftr + (size_t)(m0 + srow) * NLON + n0 + skc);
    *(h8*)&Ai[srow][skc] = *(const h8*)(Fti + (size_t)(m0 + srow) * NLON + n0 + skc);
    const float* px = x + (size_t)(r0 + srow) * NLON + n0 + skc;
    float4 v0 = *(const float4*)px;
    float4 v1 = *(const float4*)(px + 4);
    h8 hx = {(f16)v0.x, (f16)v0.y, (f16)v0.z, (f16)v0.w,
             (f16)v1.x, (f16)v1.y, (f16)v1.z, (f16)v1.w};
    *(h8*)&Bx[srow][skc] = hx;
    __syncthreads();
    h8 a0 = *(h8*)&Ar[wm + fr][kg],      a1 = *(h8*)&Ar[wm + 16 + fr][kg];
    h8 c0 = *(h8*)&Ai[wm + fr][kg],      c1 = *(h8*)&Ai[wm + 16 + fr][kg];
    h8 b0 = *(h8*)&Bx[wn + fr][kg],      b1 = *(h8*)&Bx[wn + 16 + fr][kg];
    aR[0][0] = mfma16(a0, b0, aR[0][0]); aR[0][1] = mfma16(a0, b1, aR[0][1]);
    aR[1][0] = mfma16(a1, b0, aR[1][0]); aR[1][1] = mfma16(a1, b1, aR[1][1]);
    aI[0][0] = mfma16(c0, b0, aI[0][0]); aI[0][1] = mfma16(c0, b1, aI[0][1]);
    aI[1][0] = mfma16(c1, b0, aI[1][0]); aI[1][1] = mfma16(c1, b1, aI[1][1]);
    __syncthreads();
  }
  int drow = (lane >> 4) * 4, dcol = lane & 15;
#pragma unroll
  for (int i = 0; i < 2; ++i)
#pragma unroll
    for (int j = 0; j < 2; ++j)
#pragma unroll
      for (int b = 0; b < 4; ++b) {
        size_t o = (size_t)(m0 + wm + i * 16 + drow + b) * RTOT + r0 + wn + j * 16 + dcol;
        XFre[o] = (f16)aR[i][j][b];
        XFim[o] = (f16)aI[i][j][b];
      }
}

// ---- S2 (per m): C[c][l] = sum_k XF[m][c][k]*shtw[m][l][k]; writes P[l][m][c] ----
__global__ __launch_bounds__(256) void k_s2(
    const f16* __restrict__ XFre, const f16* __restrict__ XFim,
    const float* __restrict__ shtw, f16* __restrict__ Pre, f16* __restrict__ Pim) {
  int m = blockIdx.y;
  int l0 = blockIdx.x * 64;
  int t = threadIdx.x;
  if (l0 + 64 <= m) {  // exactly-zero tile
    h8 z = {};
#pragma unroll
    for (int rep = 0; rep < 2; ++rep) {
      int f = rep * 256 + t;
      int ll = f >> 3, c8 = (f & 7) * 8;
      size_t o = (size_t)(l0 + ll) * RTOT + (size_t)m * 64 + c8;
      *(h8*)(Pre + o) = z;
      *(h8*)(Pim + o) = z;
    }
    return;
  }
  __shared__ f16 SH[9216];  // stage 3*2560=7680; epilogue 2*4608=9216
  f16* Ar = SH;             // [64][40] rows=c
  f16* Ai = SH + 2560;
  f16* Bs = SH + 5120;      // [64][40] rows=l
  int lane = t & 63, w = t >> 6;
  int wm = (w >> 1) * 32, wn = (w & 1) * 32;
  int fr = lane & 15, kg = (lane >> 4) * 8;
  int srow = t >> 2, skc = (t & 3) * 8;
  const f16* Abr = XFre + (size_t)m * RTOT;
  const f16* Abi = XFim + (size_t)m * RTOT;
  const float* Bb = shtw + (size_t)m * (NL * NLAT);
  f4 aR[2][2] = {}, aI[2][2] = {};
  for (int k0 = 0; k0 < NLAT; k0 += 32) {
    *(h8*)&Ar[srow * 40 + skc] = *(const h8*)(Abr + (size_t)srow * NLAT + k0 + skc);
    *(h8*)&Ai[srow * 40 + skc] = *(const h8*)(Abi + (size_t)srow * NLAT + k0 + skc);
    const float* pb = Bb + (size_t)(l0 + srow) * NLAT + k0 + skc;
    float4 v0 = *(const float4*)pb;
    float4 v1 = *(const float4*)(pb + 4);
    h8 hb = {(f16)v0.x, (f16)v0.y, (f16)v0.z, (f16)v0.w,
             (f16)v1.x, (f16)v1.y, (f16)v1.z, (f16)v1.w};
    *(h8*)&Bs[srow * 40 + skc] = hb;
    __syncthreads();
    h8 a0 = *(h8*)&Ar[(wm + fr) * 40 + kg],      a1 = *(h8*)&Ar[(wm + 16 + fr) * 40 + kg];
    h8 c0 = *(h8*)&Ai[(wm + fr) * 40 + kg],      c1 = *(h8*)&Ai[(wm + 16 + fr) * 40 + kg];
    h8 b0 = *(h8*)&Bs[(wn + fr) * 40 + kg],      b1 = *(h8*)&Bs[(wn + 16 + fr) * 40 + kg];
    aR[0][0] = mfma16(a0, b0, aR[0][0]); aR[0][1] = mfma16(a0, b1, aR[0][1]);
    aR[1][0] = mfma16(a1, b0, aR[1][0]); aR[1][1] = mfma16(a1, b1, aR[1][1]);
    aI[0][0] = mfma16(c0, b0, aI[0][0]); aI[0][1] = mfma16(c0, b1, aI[0][1]);
    aI[1][0] = mfma16(c1, b0, aI[1][0]); aI[1][1] = mfma16(c1, b1, aI[1][1]);
    __syncthreads();
  }
  // restage: T[l][c] stride 72, then coalesced h8 writes to P[l][m][c]
  f16* Tr = SH;
  f16* Ti = SH + 4608;
  int drow = (lane >> 4) * 4, dcol = lane & 15;
#pragma unroll
  for (int i = 0; i < 2; ++i)
#pragma unroll
    for (int j = 0; j < 2; ++j)
#pragma unroll
      for (int b = 0; b < 4; ++b) {
        int c = wm + i * 16 + drow + b;
        int l = wn + j * 16 + dcol;
        Tr[l * 72 + c] = (f16)aR[i][j][b];
        Ti[l * 72 + c] = (f16)aI[i][j][b];
      }
  __syncthreads();
#pragma unroll
  for (int rep = 0; rep < 4; ++rep) {
    int f = rep * 256 + t;
    int buf = f >> 9, idx = f & 511;
    int ll = idx >> 3, c8 = (idx & 7) * 8;
    const f16* T = buf ? Ti : Tr;
    h8 v = *(const h8*)&T[ll * 72 + c8];
    f16* Pd = buf ? Pim : Pre;
    *(h8*)(Pd + (size_t)(l0 + ll) * RTOT + (size_t)m * 64 + c8) = v;
  }
}

// ---- S3 (per l): O[m][o] = sum_i P[l][m][i]*wT[l][o][i] (complex); out Q[l][m][o] ----
__global__ __launch_bounds__(256) void k_s3(
    const f16* __restrict__ Pre, const f16* __restrict__ Pim,
    const f16* __restrict__ wTr, const f16* __restrict__ wTi,
    f16* __restrict__ Qre, f16* __restrict__ Qim) {
  int l = blockIdx.y;
  int m0 = blockIdx.x * 64;
  int t = threadIdx.x;
  size_t obase = (size_t)l * RTOT + (size_t)m0 * 64;  // contiguous 4096-f16 tile
  if (m0 > l) {  // coeffs zero for m > l
    h8 z = {};
#pragma unroll
    for (int rep = 0; rep < 2; ++rep) {
      int f = rep * 256 + t;
      ((h8*)(Qre + obase))[f] = z;
      ((h8*)(Qim + obase))[f] = z;
    }
    return;
  }
  __shared__ f16 SH[18432];  // 4 tiles [64][72]
  f16* Ar = SH;
  f16* Ai = SH + 4608;
  f16* Br = SH + 9216;
  f16* Bi = SH + 13824;
  const f16* Pbr = Pre + (size_t)l * RTOT + (size_t)m0 * 64;
  const f16* Pbi = Pim + (size_t)l * RTOT + (size_t)m0 * 64;
  const f16* Wbr = wTr + (size_t)l * 4096;
  const f16* Wbi = wTi + (size_t)l * 4096;
#pragma unroll
  for (int rep = 0; rep < 2; ++rep) {
    int f = rep * 256 + t;
    int row = f >> 3, c8 = (f & 7) * 8;
    *(h8*)&Ar[row * 72 + c8] = *(const h8*)(Pbr + (size_t)row * 64 + c8);
    *(h8*)&Ai[row * 72 + c8] = *(const h8*)(Pbi + (size_t)row * 64 + c8);
    *(h8*)&Br[row * 72 + c8] = *(const h8*)(Wbr + (size_t)f * 8);
    *(h8*)&Bi[row * 72 + c8] = *(const h8*)(Wbi + (size_t)f * 8);
  }
  __syncthreads();
  int lane = t & 63, w = t >> 6;
  int wm = (w >> 1) * 32, wn = (w & 1) * 32;
  int fr = lane & 15, kg = (lane >> 4) * 8;
  f4 RR[2][2] = {}, II[2][2] = {}, RI[2][2] = {}, IR[2][2] = {};
#pragma unroll
  for (int ks = 0; ks < 64; ks += 32) {
    h8 a0 = *(h8*)&Ar[(wm + fr) * 72 + ks + kg];
    h8 a1 = *(h8*)&Ar[(wm + 16 + fr) * 72 + ks + kg];
    h8 c0 = *(h8*)&Ai[(wm + fr) * 72 + ks + kg];
    h8 c1 = *(h8*)&Ai[(wm + 16 + fr) * 72 + ks + kg];
    h8 b0 = *(h8*)&Br[(wn + fr) * 72 + ks + kg];
    h8 b1 = *(h8*)&Br[(wn + 16 + fr) * 72 + ks + kg];
    h8 d0 = *(h8*)&Bi[(wn + fr) * 72 + ks + kg];
    h8 d1 = *(h8*)&Bi[(wn + 16 + fr) * 72 + ks + kg];
    RR[0][0] = mfma16(a0, b0, RR[0][0]); RR[0][1] = mfma16(a0, b1, RR[0][1]);
    RR[1][0] = mfma16(a1, b0, RR[1][0]); RR[1][1] = mfma16(a1, b1, RR[1][1]);
    II[0][0] = mfma16(c0, d0, II[0][0]); II[0][1] = mfma16(c0, d1, II[0][1]);
    II[1][0] = mfma16(c1, d0, II[1][0]); II[1][1] = mfma16(c1, d1, II[1][1]);
    RI[0][0] = mfma16(a0, d0, RI[0][0]); RI[0][1] = mfma16(a0, d1, RI[0][1]);
    RI[1][0] = mfma16(a1, d0, RI[1][0]); RI[1][1] = mfma16(a1, d1, RI[1][1]);
    IR[0][0] = mfma16(c0, b0, IR[0][0]); IR[0][1] = mfma16(c0, b1, IR[0][1]);
    IR[1][0] = mfma16(c1, b0, IR[1][0]); IR[1][1] = mfma16(c1, b1, IR[1][1]);
  }
  __syncthreads();
  // restage T[m][o] stride 72 then contiguous h8 writes
  f16* Tr = SH;
  f16* Ti = SH + 4608;
  int drow = (lane >> 4) * 4, dcol = lane & 15;
#pragma unroll
  for (int i = 0; i < 2; ++i)
#pragma unroll
    for (int j = 0; j < 2; ++j)
#pragma unroll
      for (int b = 0; b < 4; ++b) {
        int mm = wm + i * 16 + drow + b;
        int oo = wn + j * 16 + dcol;
        Tr[mm * 72 + oo] = (f16)(RR[i][j][b] - II[i][j][b]);
        Ti[mm * 72 + oo] = (f16)(RI[i][j][b] + IR[i][j][b]);
      }
  __syncthreads();
#pragma unroll
  for (int rep = 0; rep < 4; ++rep) {
    int f = rep * 256 + t;
    int buf = f >> 9, idx = f & 511;
    int mm = idx >> 3, o8 = (idx & 7) * 8;
    const f16* T = buf ? Ti : Tr;
    h8 v = *(const h8*)&T[mm * 72 + o8];
    f16* Qd = buf ? Qim : Qre;
    *(h8*)(Qd + obase + (size_t)mm * 64 + o8) = v;
  }
}

// ---- S4 (per m): XK[m][o][k] = sum_l Q[l][m][o]*pct[m][l][k] ----
__global__ __launch_bounds__(256) void k_s4(
    const f16* __restrict__ Qre, const f16* __restrict__ Qim,
    const float* __restrict__ pct, f16* __restrict__ XKre, f16* __restrict__ XKim) {
  __shared__ f16 As[2560], Ais[2560], Bs[2560];  // [64][40]
  int m = blockIdx.y;
  int k0b = blockIdx.x * 64;
  int t = threadIdx.x;
  int lane = t & 63, w = t >> 6;
  int wm = (w >> 1) * 32, wn = (w & 1) * 32;
  int fr = lane & 15, kg = (lane >> 4) * 8;
  const float* Bb = pct + (size_t)m * (NL * NLAT);
  f4 aR[2][2] = {}, aI[2][2] = {};
  int lstart = m & ~31;  // pct[m][l<m]=0; Q zero there too
  int lr = t >> 3, o8 = (t & 7) * 8;
  int kcc = (t & 7) * 8;
  for (int l0 = lstart; l0 < NL; l0 += 32) {
    // A: Q[l0+lr][m][o8..o8+7] -> As[o][lr] (transpose scatter)
    h8 vr = *(const h8*)(Qre + (size_t)(l0 + lr) * RTOT + (size_t)m * 64 + o8);
    h8 vi = *(const h8*)(Qim + (size_t)(l0 + lr) * RTOT + (size_t)m * 64 + o8);
#pragma unroll
    for (int e = 0; e < 8; ++e) {
      As[(o8 + e) * 40 + lr] = vr[e];
      Ais[(o8 + e) * 40 + lr] = vi[e];
    }
    // B: pct[m][l0+lr][k0b+kcc..] -> Bs[k][lr]
    const float* pb = Bb + (size_t)(l0 + lr) * NLAT + k0b + kcc;
    float4 v0 = *(const float4*)pb;
    float4 v1 = *(const float4*)(pb + 4);
    float vv[8] = {v0.x, v0.y, v0.z, v0.w, v1.x, v1.y, v1.z, v1.w};
#pragma unroll
    for (int e = 0; e < 8; ++e) Bs[(kcc + e) * 40 + lr] = (f16)vv[e];
    __syncthreads();
    h8 a0 = *(h8*)&As[(wm + fr) * 40 + kg],  a1 = *(h8*)&As[(wm + 16 + fr) * 40 + kg];
    h8 c0 = *(h8*)&Ais[(wm + fr) * 40 + kg], c1 = *(h8*)&Ais[(wm + 16 + fr) * 40 + kg];
    h8 b0 = *(h8*)&Bs[(wn + fr) * 40 + kg],  b1 = *(h8*)&Bs[(wn + 16 + fr) * 40 + kg];
    aR[0][0] = mfma16(a0, b0, aR[0][0]); aR[0][1] = mfma16(a0, b1, aR[0][1]);
    aR[1][0] = mfma16(a1, b0, aR[1][0]); aR[1][1] = mfma16(a1, b1, aR[1][1]);
    aI[0][0] = mfma16(c0, b0, aI[0][0]); aI[0][1] = mfma16(c0, b1, aI[0][1]);
    aI[1][0] = mfma16(c1, b0, aI[1][0]); aI[1][1] = mfma16(c1, b1, aI[1][1]);
    __syncthreads();
  }
  int drow = (lane >> 4) * 4, dcol = lane & 15;
#pragma unroll
  for (int i = 0; i < 2; ++i)
#pragma unroll
    for (int j = 0; j < 2; ++j)
#pragma unroll
      for (int b = 0; b < 4; ++b) {
        size_t o = (size_t)m * RTOT + (size_t)(wm + i * 16 + drow + b) * NLAT + k0b + wn + j * 16 + dcol;
        XKre[o] = (f16)aR[i][j][b];
        XKim[o] = (f16)aI[i][j][b];
      }
}

// ---- S5: y[r][n] = sum_m XK[m][r]*Gr[n][m] + XKim[m][r]*Gi[n][m] ----
__global__ __launch_bounds__(256) void k_s5(
    const f16* __restrict__ XKre, const f16* __restrict__ XKim,
    const f16* __restrict__ Gr, const f16* __restrict__ Gi,
    float* __restrict__ y) {
  __shared__ f16 Ar[2560], Ai[2560], Br[2560], Bi[2560];  // [64][40]
  int t = threadIdx.x;
  int n0 = blockIdx.x * 64, r0 = blockIdx.y * 64;
  int lane = t & 63, w = t >> 6;
  int wm = (w >> 1) * 32, wn = (w & 1) * 32;
  int fr = lane & 15, kg = (lane >> 4) * 8;
  int mr = t >> 3, r8 = (t & 7) * 8;
  int srow = t >> 2, skc = (t & 3) * 8;
  f4 acc[2][2] = {};
  for (int m0 = 0; m0 < NM; m0 += 32) {
    // A: XK[m0+mr][r0+r8..] -> Ar[r][mr] (transpose scatter)
    h8 vr = *(const h8*)(XKre + (size_t)(m0 + mr) * RTOT + r0 + r8);
    h8 vi = *(const h8*)(XKim + (size_t)(m0 + mr) * RTOT + r0 + r8);
#pragma unroll
    for (int e = 0; e < 8; ++e) {
      Ar[(r8 + e) * 40 + mr] = vr[e];
      Ai[(r8 + e) * 40 + mr] = vi[e];
    }
    *(h8*)&Br[srow * 40 + skc] = *(const h8*)(Gr + (size_t)(n0 + srow) * NM + m0 + skc);
    *(h8*)&Bi[srow * 40 + skc] = *(const h8*)(Gi + (size_t)(n0 + srow) * NM + m0 + skc);
    __syncthreads();
    h8 a0 = *(h8*)&Ar[(wm + fr) * 40 + kg], a1 = *(h8*)&Ar[(wm + 16 + fr) * 40 + kg];
    h8 c0 = *(h8*)&Ai[(wm + fr) * 40 + kg], c1 = *(h8*)&Ai[(wm + 16 + fr) * 40 + kg];
    h8 b0 = *(h8*)&Br[(wn + fr) * 40 + kg], b1 = *(h8*)&Br[(wn + 16 + fr) * 40 + kg];
    h8 d0 = *(h8*)&Bi[(wn + fr) * 40 + kg], d1 = *(h8*)&Bi[(wn + 16 + fr) * 40 + kg];
    acc[0][0] = mfma16(a0, b0, acc[0][0]); acc[0][1] = mfma16(a0, b1, acc[0][1]);
    acc[1][0] = mfma16(a1, b0, acc[1][0]); acc[1][1] = mfma16(a1, b1, acc[1][1]);
    acc[0][0] = mfma16(c0, d0, acc[0][0]); acc[0][1] = mfma16(c0, d1, acc[0][1]);
    acc[1][0] = mfma16(c1, d0, acc[1][0]); acc[1][1] = mfma16(c1, d1, acc[1][1]);
    __syncthreads();
  }
  int drow = (lane >> 4) * 4, dcol = lane & 15;
#pragma unroll
  for (int i = 0; i < 2; ++i)
#pragma unroll
    for (int j = 0; j < 2; ++j)
#pragma unroll
      for (int b = 0; b < 4; ++b)
        y[(size_t)(r0 + wm + i * 16 + drow + b) * NLON + n0 + wn + j * 16 + dcol] = acc[i][j][b];
}

extern "C" void kernel_launch(void* const* d_in, const int* in_sizes, int n_in,
                              void* d_out, int out_size, void* d_ws, size_t ws_size,
                              hipStream_t stream) {
  const float* x    = (const float*)d_in[0];
  const float* wgr  = (const float*)d_in[1];
  const float* wgi  = (const float*)d_in[2];
  const float* pct  = (const float*)d_in[3];
  const float* shtw = (const float*)d_in[4];
  float* out = (float*)d_out;
  char* ws = (char*)d_ws;

  f16* Ftr = (f16*)(ws + BO_FTR);
  f16* Fti = (f16*)(ws + BO_FTI);
  f16* Gr  = (f16*)(ws + BO_GR);
  f16* Gi  = (f16*)(ws + BO_GI);
  f16* wTr = (f16*)(ws + BO_WTR);
  f16* wTi = (f16*)(ws + BO_WTI);
  f16* XFre = (f16*)(ws + BO_XFRE);  // XF, later XK
  f16* XFim = (f16*)(ws + BO_XFIM);
  f16* Pre  = (f16*)(ws + BO_PRE);
  f16* Pim  = (f16*)(ws + BO_PIM);
  f16* Qre  = (f16*)(ws + BO_QRE);
  f16* Qim  = (f16*)(ws + BO_QIM);

  hipLaunchKernelGGL(k_tables_h, dim3(512), dim3(256), 0, stream, Ftr, Fti, Gr, Gi);
  hipLaunchKernelGGL(k_permw_h, dim3(8, 2, 64), dim3(32, 8), 0, stream, wgr, wTr);
  hipLaunchKernelGGL(k_permw_h, dim3(8, 2, 64), dim3(32, 8), 0, stream, wgi, wTi);
  // S1: forward DFT -> XF[m][c][k]
  hipLaunchKernelGGL(k_s1, dim3(4, 256), dim3(256), 0, stream, x, Ftr, Fti, XFre, XFim);
  // S2: forward Legendre -> P[l][m][c]
  hipLaunchKernelGGL(k_s2, dim3(4, 256), dim3(256), 0, stream, XFre, XFim, shtw, Pre, Pim);
  // S3: per-l weight GEMM -> Q[l][m][o]
  hipLaunchKernelGGL(k_s3, dim3(4, 256), dim3(256), 0, stream, Pre, Pim, wTr, wTi, Qre, Qim);
  // S4: inverse Legendre -> XK[m][o][k] (into XF region)
  hipLaunchKernelGGL(k_s4, dim3(4, 256), dim3(256), 0, stream, Qre, Qim, pct, XFre, XFim);
  // S5: inverse DFT -> y
  hipLaunchKernelGGL(k_s5, dim3(8, 256), dim3(256), 0, stream, XFre, XFim, Gr, Gi, out);
  // residual passthrough
  hipMemcpyAsync(out + (size_t)NC * NLAT * NLON, x,
                 sizeof(float) * NC * NLAT * NLON, hipMemcpyDeviceToDevice, stream);
}

// Round 4
// 134.681 us; speedup vs baseline: 3.0486x; 1.1020x over previous
//
#include <hip/hip_runtime.h>

typedef _Float16 f16;
typedef _Float16 h8 __attribute__((ext_vector_type(8)));
typedef float f4 __attribute__((ext_vector_type(4)));

#define NLON 512
#define NLAT 256
#define NC   64
#define NM   256
#define NL   256
#define RTOT (NC*NLAT)   // 16384

// ---- workspace byte offsets ----
#define BO_FTR 0
#define BO_FTI (BO_FTR + 262144)
#define BO_GR  (BO_FTI + 262144)
#define BO_GI  (BO_GR  + 262144)
#define BO_WTR (BO_GI  + 262144)
#define BO_WTI (BO_WTR + 2097152)
#define BO_XFRE (BO_WTI + 2097152)   // f16 [m][c][k] — reused as XK [m][o][k]
#define BO_XFIM (BO_XFRE + 8388608)
#define BO_PRE  (BO_XFIM + 8388608)  // f16 P [l][m][c]
#define BO_PIM  (BO_PRE + 8388608)
#define BO_QRE  (BO_PIM + 8388608)   // f16 Q [l][m][o]
#define BO_QIM  (BO_QRE + 8388608)
// end: 55574528 bytes (~53 MB)

__device__ inline f4 mfma16(h8 a, h8 b, f4 c) {
  return __builtin_amdgcn_mfma_f32_16x16x32_f16(a, b, c, 0, 0, 0);
}

// ---- tables: Ftr/Fti [m=256][n=512], Gr/Gi [n=512][m=256], all f16 ----
__global__ void k_tables_h(f16* __restrict__ Ftr, f16* __restrict__ Fti,
                           f16* __restrict__ Gr, f16* __restrict__ Gi) {
  int idx = blockIdx.x * blockDim.x + threadIdx.x;
  if (idx >= NLON * NM) return;
  const float step = 3.14159265358979323846f / 256.0f;
  {
    int m = idx >> 9, n = idx & 511;
    int t = (n * m) & (NLON - 1);
    float th = t * step;
    const float sc = 6.2831853071795864769f / 512.0f;
    Ftr[idx] = (f16)(sc * cosf(th));
    Fti[idx] = (f16)(-sc * sinf(th));
  }
  {
    int n = idx >> 8, m = idx & 255;
    int t = (n * m) & (NLON - 1);
    float th = t * step;
    float s = (m == 0) ? 1.0f : 2.0f;
    Gr[idx] = (f16)(s * cosf(th));
    Gi[idx] = (f16)(-s * sinf(th));
  }
}

// w [i][o][l] f32 -> wT [l][o][i] f16
__global__ void k_permw_h(const float* __restrict__ w, f16* __restrict__ wT) {
  __shared__ float tile[32][33];
  int o = blockIdx.z;
  int i0 = blockIdx.y * 32;
  int l0 = blockIdx.x * 32;
  int xx = threadIdx.x, yy = threadIdx.y;
  for (int j = 0; j < 32; j += 8)
    tile[yy + j][xx] = w[(size_t)(i0 + yy + j) * (NC * NL) + (size_t)o * NL + l0 + xx];
  __syncthreads();
  for (int j = 0; j < 32; j += 8)
    wT[(size_t)(l0 + yy + j) * (NC * NC) + (size_t)o * NC + i0 + xx] = (f16)tile[xx][yy + j];
}

// ---- S1: XF[m][c][k] = sum_n F[m][n] * x[(c,k)][n] ----
__global__ __launch_bounds__(256) void k_s1(
    const float* __restrict__ x, const f16* __restrict__ Ftr,
    const f16* __restrict__ Fti, f16* __restrict__ XFre, f16* __restrict__ XFim) {
  __shared__ f16 Ar[64][40], Ai[64][40], Bx[64][40];
  int t = threadIdx.x;
  int m0 = blockIdx.x * 64, r0 = blockIdx.y * 64;
  int lane = t & 63, w = t >> 6;
  int wm = (w >> 1) * 32, wn = (w & 1) * 32;
  int fr = lane & 15, kg = (lane >> 4) * 8;
  int srow = t >> 2, skc = (t & 3) * 8;
  f4 aR[2][2] = {}, aI[2][2] = {};
  for (int n0 = 0; n0 < NLON; n0 += 32) {
    *(h8*)&Ar[srow][skc] = *(const h8*)(Ftr + (size_t)(m0 + srow) * NLON + n0 + skc);
    *(h8*)&Ai[srow][skc] = *(const h8*)(Fti + (size_t)(m0 + srow) * NLON + n0 + skc);
    const float* px = x + (size_t)(r0 + srow) * NLON + n0 + skc;
    float4 v0 = *(const float4*)px;
    float4 v1 = *(const float4*)(px + 4);
    h8 hx = {(f16)v0.x, (f16)v0.y, (f16)v0.z, (f16)v0.w,
             (f16)v1.x, (f16)v1.y, (f16)v1.z, (f16)v1.w};
    *(h8*)&Bx[srow][skc] = hx;
    __syncthreads();
    h8 a0 = *(h8*)&Ar[wm + fr][kg],      a1 = *(h8*)&Ar[wm + 16 + fr][kg];
    h8 c0 = *(h8*)&Ai[wm + fr][kg],      c1 = *(h8*)&Ai[wm + 16 + fr][kg];
    h8 b0 = *(h8*)&Bx[wn + fr][kg],      b1 = *(h8*)&Bx[wn + 16 + fr][kg];
    aR[0][0] = mfma16(a0, b0, aR[0][0]); aR[0][1] = mfma16(a0, b1, aR[0][1]);
    aR[1][0] = mfma16(a1, b0, aR[1][0]); aR[1][1] = mfma16(a1, b1, aR[1][1]);
    aI[0][0] = mfma16(c0, b0, aI[0][0]); aI[0][1] = mfma16(c0, b1, aI[0][1]);
    aI[1][0] = mfma16(c1, b0, aI[1][0]); aI[1][1] = mfma16(c1, b1, aI[1][1]);
    __syncthreads();
  }
  int drow = (lane >> 4) * 4, dcol = lane & 15;
#pragma unroll
  for (int i = 0; i < 2; ++i)
#pragma unroll
    for (int j = 0; j < 2; ++j)
#pragma unroll
      for (int b = 0; b < 4; ++b) {
        size_t o = (size_t)(m0 + wm + i * 16 + drow + b) * RTOT + r0 + wn + j * 16 + dcol;
        XFre[o] = (f16)aR[i][j][b];
        XFim[o] = (f16)aI[i][j][b];
      }
}

// ---- S2 (per m): C[c][l] = sum_k XF[m][c][k]*shtw[m][l][k]; writes P[l][m][c] ----
__global__ __launch_bounds__(256) void k_s2(
    const f16* __restrict__ XFre, const f16* __restrict__ XFim,
    const float* __restrict__ shtw, f16* __restrict__ Pre, f16* __restrict__ Pim) {
  int m = blockIdx.y;
  int l0 = blockIdx.x * 64;
  int t = threadIdx.x;
  if (l0 + 64 <= m) {  // exactly-zero tile
    h8 z = {};
#pragma unroll
    for (int rep = 0; rep < 2; ++rep) {
      int f = rep * 256 + t;
      int ll = f >> 3, c8 = (f & 7) * 8;
      size_t o = (size_t)(l0 + ll) * RTOT + (size_t)m * 64 + c8;
      *(h8*)(Pre + o) = z;
      *(h8*)(Pim + o) = z;
    }
    return;
  }
  __shared__ f16 SH[9216];  // stage 3*2560=7680; epilogue 2*4608=9216
  f16* Ar = SH;             // [64][40] rows=c
  f16* Ai = SH + 2560;
  f16* Bs = SH + 5120;      // [64][40] rows=l
  int lane = t & 63, w = t >> 6;
  int wm = (w >> 1) * 32, wn = (w & 1) * 32;
  int fr = lane & 15, kg = (lane >> 4) * 8;
  int srow = t >> 2, skc = (t & 3) * 8;
  const f16* Abr = XFre + (size_t)m * RTOT;
  const f16* Abi = XFim + (size_t)m * RTOT;
  const float* Bb = shtw + (size_t)m * (NL * NLAT);
  f4 aR[2][2] = {}, aI[2][2] = {};
  for (int k0 = 0; k0 < NLAT; k0 += 32) {
    *(h8*)&Ar[srow * 40 + skc] = *(const h8*)(Abr + (size_t)srow * NLAT + k0 + skc);
    *(h8*)&Ai[srow * 40 + skc] = *(const h8*)(Abi + (size_t)srow * NLAT + k0 + skc);
    const float* pb = Bb + (size_t)(l0 + srow) * NLAT + k0 + skc;
    float4 v0 = *(const float4*)pb;
    float4 v1 = *(const float4*)(pb + 4);
    h8 hb = {(f16)v0.x, (f16)v0.y, (f16)v0.z, (f16)v0.w,
             (f16)v1.x, (f16)v1.y, (f16)v1.z, (f16)v1.w};
    *(h8*)&Bs[srow * 40 + skc] = hb;
    __syncthreads();
    h8 a0 = *(h8*)&Ar[(wm + fr) * 40 + kg],      a1 = *(h8*)&Ar[(wm + 16 + fr) * 40 + kg];
    h8 c0 = *(h8*)&Ai[(wm + fr) * 40 + kg],      c1 = *(h8*)&Ai[(wm + 16 + fr) * 40 + kg];
    h8 b0 = *(h8*)&Bs[(wn + fr) * 40 + kg],      b1 = *(h8*)&Bs[(wn + 16 + fr) * 40 + kg];
    aR[0][0] = mfma16(a0, b0, aR[0][0]); aR[0][1] = mfma16(a0, b1, aR[0][1]);
    aR[1][0] = mfma16(a1, b0, aR[1][0]); aR[1][1] = mfma16(a1, b1, aR[1][1]);
    aI[0][0] = mfma16(c0, b0, aI[0][0]); aI[0][1] = mfma16(c0, b1, aI[0][1]);
    aI[1][0] = mfma16(c1, b0, aI[1][0]); aI[1][1] = mfma16(c1, b1, aI[1][1]);
    __syncthreads();
  }
  // restage: T[l][c] stride 72, then coalesced h8 writes to P[l][m][c]
  f16* Tr = SH;
  f16* Ti = SH + 4608;
  int drow = (lane >> 4) * 4, dcol = lane & 15;
#pragma unroll
  for (int i = 0; i < 2; ++i)
#pragma unroll
    for (int j = 0; j < 2; ++j)
#pragma unroll
      for (int b = 0; b < 4; ++b) {
        int c = wm + i * 16 + drow + b;
        int l = wn + j * 16 + dcol;
        Tr[l * 72 + c] = (f16)aR[i][j][b];
        Ti[l * 72 + c] = (f16)aI[i][j][b];
      }
  __syncthreads();
#pragma unroll
  for (int rep = 0; rep < 4; ++rep) {
    int f = rep * 256 + t;
    int buf = f >> 9, idx = f & 511;
    int ll = idx >> 3, c8 = (idx & 7) * 8;
    const f16* T = buf ? Ti : Tr;
    h8 v = *(const h8*)&T[ll * 72 + c8];
    f16* Pd = buf ? Pim : Pre;
    *(h8*)(Pd + (size_t)(l0 + ll) * RTOT + (size_t)m * 64 + c8) = v;
  }
}

// ---- S3 (per l): O[m][o] = sum_i P[l][m][i]*wT[l][o][i] (complex); out Q[l][m][o] ----
__global__ __launch_bounds__(256) void k_s3(
    const f16* __restrict__ Pre, const f16* __restrict__ Pim,
    const f16* __restrict__ wTr, const f16* __restrict__ wTi,
    f16* __restrict__ Qre, f16* __restrict__ Qim) {
  int l = blockIdx.y;
  int m0 = blockIdx.x * 64;
  int t = threadIdx.x;
  size_t obase = (size_t)l * RTOT + (size_t)m0 * 64;  // contiguous 4096-f16 tile
  if (m0 > l) {  // coeffs zero for m > l
    h8 z = {};
#pragma unroll
    for (int rep = 0; rep < 2; ++rep) {
      int f = rep * 256 + t;
      ((h8*)(Qre + obase))[f] = z;
      ((h8*)(Qim + obase))[f] = z;
    }
    return;
  }
  __shared__ f16 SH[18432];  // 4 tiles [64][72]
  f16* Ar = SH;
  f16* Ai = SH + 4608;
  f16* Br = SH + 9216;
  f16* Bi = SH + 13824;
  const f16* Pbr = Pre + (size_t)l * RTOT + (size_t)m0 * 64;
  const f16* Pbi = Pim + (size_t)l * RTOT + (size_t)m0 * 64;
  const f16* Wbr = wTr + (size_t)l * 4096;
  const f16* Wbi = wTi + (size_t)l * 4096;
#pragma unroll
  for (int rep = 0; rep < 2; ++rep) {
    int f = rep * 256 + t;
    int row = f >> 3, c8 = (f & 7) * 8;
    *(h8*)&Ar[row * 72 + c8] = *(const h8*)(Pbr + (size_t)row * 64 + c8);
    *(h8*)&Ai[row * 72 + c8] = *(const h8*)(Pbi + (size_t)row * 64 + c8);
    *(h8*)&Br[row * 72 + c8] = *(const h8*)(Wbr + (size_t)f * 8);
    *(h8*)&Bi[row * 72 + c8] = *(const h8*)(Wbi + (size_t)f * 8);
  }
  __syncthreads();
  int lane = t & 63, w = t >> 6;
  int wm = (w >> 1) * 32, wn = (w & 1) * 32;
  int fr = lane & 15, kg = (lane >> 4) * 8;
  f4 RR[2][2] = {}, II[2][2] = {}, RI[2][2] = {}, IR[2][2] = {};
#pragma unroll
  for (int ks = 0; ks < 64; ks += 32) {
    h8 a0 = *(h8*)&Ar[(wm + fr) * 72 + ks + kg];
    h8 a1 = *(h8*)&Ar[(wm + 16 + fr) * 72 + ks + kg];
    h8 c0 = *(h8*)&Ai[(wm + fr) * 72 + ks + kg];
    h8 c1 = *(h8*)&Ai[(wm + 16 + fr) * 72 + ks + kg];
    h8 b0 = *(h8*)&Br[(wn + fr) * 72 + ks + kg];
    h8 b1 = *(h8*)&Br[(wn + 16 + fr) * 72 + ks + kg];
    h8 d0 = *(h8*)&Bi[(wn + fr) * 72 + ks + kg];
    h8 d1 = *(h8*)&Bi[(wn + 16 + fr) * 72 + ks + kg];
    RR[0][0] = mfma16(a0, b0, RR[0][0]); RR[0][1] = mfma16(a0, b1, RR[0][1]);
    RR[1][0] = mfma16(a1, b0, RR[1][0]); RR[1][1] = mfma16(a1, b1, RR[1][1]);
    II[0][0] = mfma16(c0, d0, II[0][0]); II[0][1] = mfma16(c0, d1, II[0][1]);
    II[1][0] = mfma16(c1, d0, II[1][0]); II[1][1] = mfma16(c1, d1, II[1][1]);
    RI[0][0] = mfma16(a0, d0, RI[0][0]); RI[0][1] = mfma16(a0, d1, RI[0][1]);
    RI[1][0] = mfma16(a1, d0, RI[1][0]); RI[1][1] = mfma16(a1, d1, RI[1][1]);
    IR[0][0] = mfma16(c0, b0, IR[0][0]); IR[0][1] = mfma16(c0, b1, IR[0][1]);
    IR[1][0] = mfma16(c1, b0, IR[1][0]); IR[1][1] = mfma16(c1, b1, IR[1][1]);
  }
  __syncthreads();
  // restage T[m][o] stride 72 then contiguous h8 writes
  f16* Tr = SH;
  f16* Ti = SH + 4608;
  int drow = (lane >> 4) * 4, dcol = lane & 15;
#pragma unroll
  for (int i = 0; i < 2; ++i)
#pragma unroll
    for (int j = 0; j < 2; ++j)
#pragma unroll
      for (int b = 0; b < 4; ++b) {
        int mm = wm + i * 16 + drow + b;
        int oo = wn + j * 16 + dcol;
        Tr[mm * 72 + oo] = (f16)(RR[i][j][b] - II[i][j][b]);
        Ti[mm * 72 + oo] = (f16)(RI[i][j][b] + IR[i][j][b]);
      }
  __syncthreads();
#pragma unroll
  for (int rep = 0; rep < 4; ++rep) {
    int f = rep * 256 + t;
    int buf = f >> 9, idx = f & 511;
    int mm = idx >> 3, o8 = (idx & 7) * 8;
    const f16* T = buf ? Ti : Tr;
    h8 v = *(const h8*)&T[mm * 72 + o8];
    f16* Qd = buf ? Qim : Qre;
    *(h8*)(Qd + obase + (size_t)mm * 64 + o8) = v;
  }
}

// ---- S4 (per m): XK[m][o][k] = sum_l Q[l][m][o]*pct[m][l][k] ----
// Natural-orientation LDS tiles (stride 66), fragments gathered with scalar reads.
__global__ __launch_bounds__(256) void k_s4(
    const f16* __restrict__ Qre, const f16* __restrict__ Qim,
    const float* __restrict__ pct, f16* __restrict__ XKre, f16* __restrict__ XKim) {
  __shared__ f16 As[32 * 66], Ais[32 * 66], Bs[32 * 66];
  int m = blockIdx.y;
  int k0b = blockIdx.x * 64;
  int t = threadIdx.x;
  int lane = t & 63, w = t >> 6;
  int wm = (w >> 1) * 32, wn = (w & 1) * 32;
  int fr = lane & 15, kg = (lane >> 4) * 8;
  int lr = t >> 3, c8 = (t & 7) * 8;
  const float* Bb = pct + (size_t)m * (NL * NLAT);
  f4 aR[2][2] = {}, aI[2][2] = {};
  int lstart = m & ~31;  // pct[m][l<m]=0; Q zero there too
  for (int l0 = lstart; l0 < NL; l0 += 32) {
    // A: Q[l0+lr][m][c8..] h8 -> As[lr][c8] (natural [l][o])
    *(h8*)&As[lr * 66 + c8]  = *(const h8*)(Qre + (size_t)(l0 + lr) * RTOT + (size_t)m * 64 + c8);
    *(h8*)&Ais[lr * 66 + c8] = *(const h8*)(Qim + (size_t)(l0 + lr) * RTOT + (size_t)m * 64 + c8);
    // B: pct[m][l0+lr][k0b+c8..] f32x8 -> f16 -> Bs[lr][c8] (natural [l][k])
    const float* pb = Bb + (size_t)(l0 + lr) * NLAT + k0b + c8;
    float4 v0 = *(const float4*)pb;
    float4 v1 = *(const float4*)(pb + 4);
    h8 hb = {(f16)v0.x, (f16)v0.y, (f16)v0.z, (f16)v0.w,
             (f16)v1.x, (f16)v1.y, (f16)v1.z, (f16)v1.w};
    *(h8*)&Bs[lr * 66 + c8] = hb;
    __syncthreads();
    h8 a0, a1, c0, c1, b0, b1;
#pragma unroll
    for (int e = 0; e < 8; ++e) {
      int row = (kg + e) * 66;
      a0[e] = As[row + wm + fr];
      a1[e] = As[row + wm + 16 + fr];
      c0[e] = Ais[row + wm + fr];
      c1[e] = Ais[row + wm + 16 + fr];
      b0[e] = Bs[row + wn + fr];
      b1[e] = Bs[row + wn + 16 + fr];
    }
    aR[0][0] = mfma16(a0, b0, aR[0][0]); aR[0][1] = mfma16(a0, b1, aR[0][1]);
    aR[1][0] = mfma16(a1, b0, aR[1][0]); aR[1][1] = mfma16(a1, b1, aR[1][1]);
    aI[0][0] = mfma16(c0, b0, aI[0][0]); aI[0][1] = mfma16(c0, b1, aI[0][1]);
    aI[1][0] = mfma16(c1, b0, aI[1][0]); aI[1][1] = mfma16(c1, b1, aI[1][1]);
    __syncthreads();
  }
  int drow = (lane >> 4) * 4, dcol = lane & 15;
#pragma unroll
  for (int i = 0; i < 2; ++i)
#pragma unroll
    for (int j = 0; j < 2; ++j)
#pragma unroll
      for (int b = 0; b < 4; ++b) {
        size_t o = (size_t)m * RTOT + (size_t)(wm + i * 16 + drow + b) * NLAT + k0b + wn + j * 16 + dcol;
        XKre[o] = (f16)aR[i][j][b];
        XKim[o] = (f16)aI[i][j][b];
      }
}

// ---- S5: y[r][n] = sum_m XK[m][r]*Gr[n][m] + XKim[m][r]*Gi[n][m] ----
// A staged natural [m][r] stride 66 (scalar gather); B natural [n][m] stride 34 (h8).
__global__ __launch_bounds__(256) void k_s5(
    const f16* __restrict__ XKre, const f16* __restrict__ XKim,
    const f16* __restrict__ Gr, const f16* __restrict__ Gi,
    float* __restrict__ y) {
  __shared__ f16 Ar[32 * 66], Ai[32 * 66], Br[64 * 34], Bi[64 * 34];
  int t = threadIdx.x;
  int n0 = blockIdx.x * 64, r0 = blockIdx.y * 64;
  int lane = t & 63, w = t >> 6;
  int wm = (w >> 1) * 32, wn = (w & 1) * 32;
  int fr = lane & 15, kg = (lane >> 4) * 8;
  int mr = t >> 3, r8 = (t & 7) * 8;
  int srow = t >> 2, skc = (t & 3) * 8;
  f4 acc[2][2] = {};
  for (int m0 = 0; m0 < NM; m0 += 32) {
    *(h8*)&Ar[mr * 66 + r8] = *(const h8*)(XKre + (size_t)(m0 + mr) * RTOT + r0 + r8);
    *(h8*)&Ai[mr * 66 + r8] = *(const h8*)(XKim + (size_t)(m0 + mr) * RTOT + r0 + r8);
    *(h8*)&Br[srow * 34 + skc] = *(const h8*)(Gr + (size_t)(n0 + srow) * NM + m0 + skc);
    *(h8*)&Bi[srow * 34 + skc] = *(const h8*)(Gi + (size_t)(n0 + srow) * NM + m0 + skc);
    __syncthreads();
    h8 a0, a1, c0, c1;
#pragma unroll
    for (int e = 0; e < 8; ++e) {
      int row = (kg + e) * 66;
      a0[e] = Ar[row + wm + fr];
      a1[e] = Ar[row + wm + 16 + fr];
      c0[e] = Ai[row + wm + fr];
      c1[e] = Ai[row + wm + 16 + fr];
    }
    h8 b0 = *(h8*)&Br[(wn + fr) * 34 + kg], b1 = *(h8*)&Br[(wn + 16 + fr) * 34 + kg];
    h8 d0 = *(h8*)&Bi[(wn + fr) * 34 + kg], d1 = *(h8*)&Bi[(wn + 16 + fr) * 34 + kg];
    acc[0][0] = mfma16(a0, b0, acc[0][0]); acc[0][1] = mfma16(a0, b1, acc[0][1]);
    acc[1][0] = mfma16(a1, b0, acc[1][0]); acc[1][1] = mfma16(a1, b1, acc[1][1]);
    acc[0][0] = mfma16(c0, d0, acc[0][0]); acc[0][1] = mfma16(c0, d1, acc[0][1]);
    acc[1][0] = mfma16(c1, d0, acc[1][0]); acc[1][1] = mfma16(c1, d1, acc[1][1]);
    __syncthreads();
  }
  int drow = (lane >> 4) * 4, dcol = lane & 15;
#pragma unroll
  for (int i = 0; i < 2; ++i)
#pragma unroll
    for (int j = 0; j < 2; ++j)
#pragma unroll
      for (int b = 0; b < 4; ++b)
        y[(size_t)(r0 + wm + i * 16 + drow + b) * NLON + n0 + wn + j * 16 + dcol] = acc[i][j][b];
}

extern "C" void kernel_launch(void* const* d_in, const int* in_sizes, int n_in,
                              void* d_out, int out_size, void* d_ws, size_t ws_size,
                              hipStream_t stream) {
  const float* x    = (const float*)d_in[0];
  const float* wgr  = (const float*)d_in[1];
  const float* wgi  = (const float*)d_in[2];
  const float* pct  = (const float*)d_in[3];
  const float* shtw = (const float*)d_in[4];
  float* out = (float*)d_out;
  char* ws = (char*)d_ws;

  f16* Ftr = (f16*)(ws + BO_FTR);
  f16* Fti = (f16*)(ws + BO_FTI);
  f16* Gr  = (f16*)(ws + BO_GR);
  f16* Gi  = (f16*)(ws + BO_GI);
  f16* wTr = (f16*)(ws + BO_WTR);
  f16* wTi = (f16*)(ws + BO_WTI);
  f16* XFre = (f16*)(ws + BO_XFRE);  // XF, later XK
  f16* XFim = (f16*)(ws + BO_XFIM);
  f16* Pre  = (f16*)(ws + BO_PRE);
  f16* Pim  = (f16*)(ws + BO_PIM);
  f16* Qre  = (f16*)(ws + BO_QRE);
  f16* Qim  = (f16*)(ws + BO_QIM);

  hipLaunchKernelGGL(k_tables_h, dim3(512), dim3(256), 0, stream, Ftr, Fti, Gr, Gi);
  hipLaunchKernelGGL(k_permw_h, dim3(8, 2, 64), dim3(32, 8), 0, stream, wgr, wTr);
  hipLaunchKernelGGL(k_permw_h, dim3(8, 2, 64), dim3(32, 8), 0, stream, wgi, wTi);
  // S1: forward DFT -> XF[m][c][k]
  hipLaunchKernelGGL(k_s1, dim3(4, 256), dim3(256), 0, stream, x, Ftr, Fti, XFre, XFim);
  // S2: forward Legendre -> P[l][m][c]
  hipLaunchKernelGGL(k_s2, dim3(4, 256), dim3(256), 0, stream, XFre, XFim, shtw, Pre, Pim);
  // S3: per-l weight GEMM -> Q[l][m][o]
  hipLaunchKernelGGL(k_s3, dim3(4, 256), dim3(256), 0, stream, Pre, Pim, wTr, wTi, Qre, Qim);
  // S4: inverse Legendre -> XK[m][o][k] (into XF region)
  hipLaunchKernelGGL(k_s4, dim3(4, 256), dim3(256), 0, stream, Qre, Qim, pct, XFre, XFim);
  // S5: inverse DFT -> y
  hipLaunchKernelGGL(k_s5, dim3(8, 256), dim3(256), 0, stream, XFre, XFim, Gr, Gi, out);
  // residual passthrough
  hipMemcpyAsync(out + (size_t)NC * NLAT * NLON, x,
                 sizeof(float) * NC * NLAT * NLON, hipMemcpyDeviceToDevice, stream);
}

// Round 5
// 116.960 us; speedup vs baseline: 3.5105x; 1.1515x over previous
//
#include <hip/hip_runtime.h>

typedef _Float16 f16;
typedef _Float16 h8 __attribute__((ext_vector_type(8)));
typedef float f4 __attribute__((ext_vector_type(4)));

#define NLON 512
#define NLAT 256
#define NC   64
#define NM   256
#define NL   256
#define RTOT (NC*NLAT)   // 16384

// ---- workspace byte offsets ----
#define BO_FTR 0
#define BO_FTI (BO_FTR + 262144)
#define BO_GR  (BO_FTI + 262144)
#define BO_GI  (BO_GR  + 262144)
#define BO_WTR (BO_GI  + 262144)
#define BO_WTI (BO_WTR + 2097152)
#define BO_XFRE (BO_WTI + 2097152)   // f16 [m][c][k] — reused as XK [m][o][k]
#define BO_XFIM (BO_XFRE + 8388608)
#define BO_PRE  (BO_XFIM + 8388608)  // f16 P [l][m][c]
#define BO_PIM  (BO_PRE + 8388608)
#define BO_QRE  (BO_PIM + 8388608)   // f16 Q [l][m][o]
#define BO_QIM  (BO_QRE + 8388608)

__device__ inline f4 mfma16(h8 a, h8 b, f4 c) {
  return __builtin_amdgcn_mfma_f32_16x16x32_f16(a, b, c, 0, 0, 0);
}

// ---- tables: Ftr/Fti [m=256][n=512], Gr/Gi [n=512][m=256], all f16 ----
__global__ void k_tables_h(f16* __restrict__ Ftr, f16* __restrict__ Fti,
                           f16* __restrict__ Gr, f16* __restrict__ Gi) {
  int idx = blockIdx.x * blockDim.x + threadIdx.x;
  if (idx >= NLON * NM) return;
  const float step = 3.14159265358979323846f / 256.0f;
  {
    int m = idx >> 9, n = idx & 511;
    int t = (n * m) & (NLON - 1);
    float th = t * step;
    const float sc = 6.2831853071795864769f / 512.0f;
    Ftr[idx] = (f16)(sc * cosf(th));
    Fti[idx] = (f16)(-sc * sinf(th));
  }
  {
    int n = idx >> 8, m = idx & 255;
    int t = (n * m) & (NLON - 1);
    float th = t * step;
    float s = (m == 0) ? 1.0f : 2.0f;
    Gr[idx] = (f16)(s * cosf(th));
    Gi[idx] = (f16)(-s * sinf(th));
  }
}

// both weights: [i][o][l] f32 -> wT [l][o][i] f16 (z&1 selects re/im)
__global__ void k_permw2(const float* __restrict__ wr, const float* __restrict__ wi,
                         f16* __restrict__ wTr, f16* __restrict__ wTi) {
  __shared__ float tile[32][33];
  int z = blockIdx.z;
  int o = z >> 1;
  const float* w = (z & 1) ? wi : wr;
  f16* wT = (z & 1) ? wTi : wTr;
  int i0 = blockIdx.y * 32;
  int l0 = blockIdx.x * 32;
  int xx = threadIdx.x, yy = threadIdx.y;
  for (int j = 0; j < 32; j += 8)
    tile[yy + j][xx] = w[(size_t)(i0 + yy + j) * (NC * NL) + (size_t)o * NL + l0 + xx];
  __syncthreads();
  for (int j = 0; j < 32; j += 8)
    wT[(size_t)(l0 + yy + j) * (NC * NC) + (size_t)o * NC + i0 + xx] = (f16)tile[xx][yy + j];
}

// ---- S1: XF[m][r] = sum_n F[m][n] * x[r][n]; m-tile 128; fuses residual copy ----
__global__ __launch_bounds__(256) void k_s1(
    const float* __restrict__ x, const f16* __restrict__ Ftr,
    const f16* __restrict__ Fti, f16* __restrict__ XFre, f16* __restrict__ XFim,
    float* __restrict__ res) {
  __shared__ f16 Ar[128 * 40], Ai[128 * 40], Bx[64 * 40];
  int t = threadIdx.x;
  int m0 = blockIdx.x * 128, r0 = blockIdx.y * 64;
  int lane = t & 63, w = t >> 6;
  int wm = (w >> 1) * 32, wn = (w & 1) * 32;
  int fr = lane & 15, kg = (lane >> 4) * 8;
  int srow = t >> 2, skc = (t & 3) * 8;
  f4 aR[4][2] = {}, aI[4][2] = {};
  for (int n0 = 0; n0 < NLON; n0 += 32) {
#pragma unroll
    for (int rep = 0; rep < 2; ++rep) {
      int f = rep * 256 + t;
      int row = f >> 2, c8 = (f & 3) * 8;
      *(h8*)&Ar[row * 40 + c8] = *(const h8*)(Ftr + (size_t)(m0 + row) * NLON + n0 + c8);
      *(h8*)&Ai[row * 40 + c8] = *(const h8*)(Fti + (size_t)(m0 + row) * NLON + n0 + c8);
    }
    const float* px = x + (size_t)(r0 + srow) * NLON + n0 + skc;
    float4 v0 = *(const float4*)px;
    float4 v1 = *(const float4*)(px + 4);
    if (blockIdx.x == 0) {  // residual passthrough, written exactly once
      float* pr = res + (size_t)(r0 + srow) * NLON + n0 + skc;
      *(float4*)pr = v0;
      *(float4*)(pr + 4) = v1;
    }
    h8 hx = {(f16)v0.x, (f16)v0.y, (f16)v0.z, (f16)v0.w,
             (f16)v1.x, (f16)v1.y, (f16)v1.z, (f16)v1.w};
    *(h8*)&Bx[srow * 40 + skc] = hx;
    __syncthreads();
    h8 b0 = *(h8*)&Bx[(wn + fr) * 40 + kg];
    h8 b1 = *(h8*)&Bx[(wn + 16 + fr) * 40 + kg];
#pragma unroll
    for (int im = 0; im < 4; ++im) {
      int mrow = wm + (im >> 1) * 64 + (im & 1) * 16 + fr;
      h8 a = *(h8*)&Ar[mrow * 40 + kg];
      h8 c = *(h8*)&Ai[mrow * 40 + kg];
      aR[im][0] = mfma16(a, b0, aR[im][0]); aR[im][1] = mfma16(a, b1, aR[im][1]);
      aI[im][0] = mfma16(c, b0, aI[im][0]); aI[im][1] = mfma16(c, b1, aI[im][1]);
    }
    __syncthreads();
  }
  int drow = (lane >> 4) * 4, dcol = lane & 15;
#pragma unroll
  for (int im = 0; im < 4; ++im)
#pragma unroll
    for (int j = 0; j < 2; ++j)
#pragma unroll
      for (int b = 0; b < 4; ++b) {
        int mg = m0 + wm + (im >> 1) * 64 + (im & 1) * 16 + drow + b;
        size_t o = (size_t)mg * RTOT + r0 + wn + j * 16 + dcol;
        XFre[o] = (f16)aR[im][j][b];
        XFim[o] = (f16)aI[im][j][b];
      }
}

// ---- S2 (per m): C[c][l] = sum_k XF[m][c][k]*shtw[m][l][k]; writes P[l][m][c] ----
__global__ __launch_bounds__(256) void k_s2(
    const f16* __restrict__ XFre, const f16* __restrict__ XFim,
    const float* __restrict__ shtw, f16* __restrict__ Pre, f16* __restrict__ Pim) {
  int m = blockIdx.y;
  int l0 = blockIdx.x * 64;
  int t = threadIdx.x;
  if (l0 + 64 <= m) {  // exactly-zero tile
    h8 z = {};
#pragma unroll
    for (int rep = 0; rep < 2; ++rep) {
      int f = rep * 256 + t;
      int ll = f >> 3, c8 = (f & 7) * 8;
      size_t o = (size_t)(l0 + ll) * RTOT + (size_t)m * 64 + c8;
      *(h8*)(Pre + o) = z;
      *(h8*)(Pim + o) = z;
    }
    return;
  }
  __shared__ f16 SH[9216];
  f16* Ar = SH;             // [64][40] rows=c
  f16* Ai = SH + 2560;
  f16* Bs = SH + 5120;      // [64][40] rows=l
  int lane = t & 63, w = t >> 6;
  int wm = (w >> 1) * 32, wn = (w & 1) * 32;
  int fr = lane & 15, kg = (lane >> 4) * 8;
  int srow = t >> 2, skc = (t & 3) * 8;
  const f16* Abr = XFre + (size_t)m * RTOT;
  const f16* Abi = XFim + (size_t)m * RTOT;
  const float* Bb = shtw + (size_t)m * (NL * NLAT);
  f4 aR[2][2] = {}, aI[2][2] = {};
  for (int k0 = 0; k0 < NLAT; k0 += 32) {
    *(h8*)&Ar[srow * 40 + skc] = *(const h8*)(Abr + (size_t)srow * NLAT + k0 + skc);
    *(h8*)&Ai[srow * 40 + skc] = *(const h8*)(Abi + (size_t)srow * NLAT + k0 + skc);
    const float* pb = Bb + (size_t)(l0 + srow) * NLAT + k0 + skc;
    float4 v0 = *(const float4*)pb;
    float4 v1 = *(const float4*)(pb + 4);
    h8 hb = {(f16)v0.x, (f16)v0.y, (f16)v0.z, (f16)v0.w,
             (f16)v1.x, (f16)v1.y, (f16)v1.z, (f16)v1.w};
    *(h8*)&Bs[srow * 40 + skc] = hb;
    __syncthreads();
    h8 a0 = *(h8*)&Ar[(wm + fr) * 40 + kg],      a1 = *(h8*)&Ar[(wm + 16 + fr) * 40 + kg];
    h8 c0 = *(h8*)&Ai[(wm + fr) * 40 + kg],      c1 = *(h8*)&Ai[(wm + 16 + fr) * 40 + kg];
    h8 b0 = *(h8*)&Bs[(wn + fr) * 40 + kg],      b1 = *(h8*)&Bs[(wn + 16 + fr) * 40 + kg];
    aR[0][0] = mfma16(a0, b0, aR[0][0]); aR[0][1] = mfma16(a0, b1, aR[0][1]);
    aR[1][0] = mfma16(a1, b0, aR[1][0]); aR[1][1] = mfma16(a1, b1, aR[1][1]);
    aI[0][0] = mfma16(c0, b0, aI[0][0]); aI[0][1] = mfma16(c0, b1, aI[0][1]);
    aI[1][0] = mfma16(c1, b0, aI[1][0]); aI[1][1] = mfma16(c1, b1, aI[1][1]);
    __syncthreads();
  }
  // restage to [l][c] then coalesced h8 writes to P[l][m][c]
  f16* Tr = SH;
  f16* Ti = SH + 4608;
  int drow = (lane >> 4) * 4, dcol = lane & 15;
#pragma unroll
  for (int i = 0; i < 2; ++i)
#pragma unroll
    for (int j = 0; j < 2; ++j)
#pragma unroll
      for (int b = 0; b < 4; ++b) {
        int c = wm + i * 16 + drow + b;
        int l = wn + j * 16 + dcol;
        Tr[l * 72 + c] = (f16)aR[i][j][b];
        Ti[l * 72 + c] = (f16)aI[i][j][b];
      }
  __syncthreads();
#pragma unroll
  for (int rep = 0; rep < 4; ++rep) {
    int f = rep * 256 + t;
    int buf = f >> 9, idx = f & 511;
    int ll = idx >> 3, c8 = (idx & 7) * 8;
    const f16* T = buf ? Ti : Tr;
    h8 v = *(const h8*)&T[ll * 72 + c8];
    f16* Pd = buf ? Pim : Pre;
    *(h8*)(Pd + (size_t)(l0 + ll) * RTOT + (size_t)m * 64 + c8) = v;
  }
}

// ---- S3 (per l): O[m][o] = sum_i P[l][m][i]*wT[l][o][i] (complex); out Q[l][m][o] ----
__global__ __launch_bounds__(256) void k_s3(
    const f16* __restrict__ Pre, const f16* __restrict__ Pim,
    const f16* __restrict__ wTr, const f16* __restrict__ wTi,
    f16* __restrict__ Qre, f16* __restrict__ Qim) {
  int l = blockIdx.y;
  int m0 = blockIdx.x * 64;
  int t = threadIdx.x;
  size_t obase = (size_t)l * RTOT + (size_t)m0 * 64;
  if (m0 > l) {
    h8 z = {};
#pragma unroll
    for (int rep = 0; rep < 2; ++rep) {
      int f = rep * 256 + t;
      ((h8*)(Qre + obase))[f] = z;
      ((h8*)(Qim + obase))[f] = z;
    }
    return;
  }
  __shared__ f16 SH[18432];
  f16* Ar = SH;
  f16* Ai = SH + 4608;
  f16* Br = SH + 9216;
  f16* Bi = SH + 13824;
  const f16* Pbr = Pre + (size_t)l * RTOT + (size_t)m0 * 64;
  const f16* Pbi = Pim + (size_t)l * RTOT + (size_t)m0 * 64;
  const f16* Wbr = wTr + (size_t)l * 4096;
  const f16* Wbi = wTi + (size_t)l * 4096;
#pragma unroll
  for (int rep = 0; rep < 2; ++rep) {
    int f = rep * 256 + t;
    int row = f >> 3, c8 = (f & 7) * 8;
    *(h8*)&Ar[row * 72 + c8] = *(const h8*)(Pbr + (size_t)row * 64 + c8);
    *(h8*)&Ai[row * 72 + c8] = *(const h8*)(Pbi + (size_t)row * 64 + c8);
    *(h8*)&Br[row * 72 + c8] = *(const h8*)(Wbr + (size_t)f * 8);
    *(h8*)&Bi[row * 72 + c8] = *(const h8*)(Wbi + (size_t)f * 8);
  }
  __syncthreads();
  int lane = t & 63, w = t >> 6;
  int wm = (w >> 1) * 32, wn = (w & 1) * 32;
  int fr = lane & 15, kg = (lane >> 4) * 8;
  f4 RR[2][2] = {}, II[2][2] = {}, RI[2][2] = {}, IR[2][2] = {};
#pragma unroll
  for (int ks = 0; ks < 64; ks += 32) {
    h8 a0 = *(h8*)&Ar[(wm + fr) * 72 + ks + kg];
    h8 a1 = *(h8*)&Ar[(wm + 16 + fr) * 72 + ks + kg];
    h8 c0 = *(h8*)&Ai[(wm + fr) * 72 + ks + kg];
    h8 c1 = *(h8*)&Ai[(wm + 16 + fr) * 72 + ks + kg];
    h8 b0 = *(h8*)&Br[(wn + fr) * 72 + ks + kg];
    h8 b1 = *(h8*)&Br[(wn + 16 + fr) * 72 + ks + kg];
    h8 d0 = *(h8*)&Bi[(wn + fr) * 72 + ks + kg];
    h8 d1 = *(h8*)&Bi[(wn + 16 + fr) * 72 + ks + kg];
    RR[0][0] = mfma16(a0, b0, RR[0][0]); RR[0][1] = mfma16(a0, b1, RR[0][1]);
    RR[1][0] = mfma16(a1, b0, RR[1][0]); RR[1][1] = mfma16(a1, b1, RR[1][1]);
    II[0][0] = mfma16(c0, d0, II[0][0]); II[0][1] = mfma16(c0, d1, II[0][1]);
    II[1][0] = mfma16(c1, d0, II[1][0]); II[1][1] = mfma16(c1, d1, II[1][1]);
    RI[0][0] = mfma16(a0, d0, RI[0][0]); RI[0][1] = mfma16(a0, d1, RI[0][1]);
    RI[1][0] = mfma16(a1, d0, RI[1][0]); RI[1][1] = mfma16(a1, d1, RI[1][1]);
    IR[0][0] = mfma16(c0, b0, IR[0][0]); IR[0][1] = mfma16(c0, b1, IR[0][1]);
    IR[1][0] = mfma16(c1, b0, IR[1][0]); IR[1][1] = mfma16(c1, b1, IR[1][1]);
  }
  __syncthreads();
  f16* Tr = SH;
  f16* Ti = SH + 4608;
  int drow = (lane >> 4) * 4, dcol = lane & 15;
#pragma unroll
  for (int i = 0; i < 2; ++i)
#pragma unroll
    for (int j = 0; j < 2; ++j)
#pragma unroll
      for (int b = 0; b < 4; ++b) {
        int mm = wm + i * 16 + drow + b;
        int oo = wn + j * 16 + dcol;
        Tr[mm * 72 + oo] = (f16)(RR[i][j][b] - II[i][j][b]);
        Ti[mm * 72 + oo] = (f16)(RI[i][j][b] + IR[i][j][b]);
      }
  __syncthreads();
#pragma unroll
  for (int rep = 0; rep < 4; ++rep) {
    int f = rep * 256 + t;
    int buf = f >> 9, idx = f & 511;
    int mm = idx >> 3, o8 = (idx & 7) * 8;
    const f16* T = buf ? Ti : Tr;
    h8 v = *(const h8*)&T[mm * 72 + o8];
    f16* Qd = buf ? Qim : Qre;
    *(h8*)(Qd + obase + (size_t)mm * 64 + o8) = v;
  }
}

// ---- S4 (per m): XK[m][o][k] = sum_l Q[l][m][o]*pct[m][l][k]; k-tile 128 ----
__global__ __launch_bounds__(256) void k_s4(
    const f16* __restrict__ Qre, const f16* __restrict__ Qim,
    const float* __restrict__ pct, f16* __restrict__ XKre, f16* __restrict__ XKim) {
  __shared__ f16 As[32 * 66], Ais[32 * 66], Bs0[32 * 66], Bs1[32 * 66];
  int m = blockIdx.y;
  int k0b = blockIdx.x * 128;
  int t = threadIdx.x;
  int lane = t & 63, w = t >> 6;
  int wm = (w >> 1) * 32, wn = (w & 1) * 32;
  int fr = lane & 15, kg = (lane >> 4) * 8;
  int lr = t >> 3, c8 = (t & 7) * 8;
  const float* Bb = pct + (size_t)m * (NL * NLAT);
  f4 aR[2][4] = {}, aI[2][4] = {};
  int lstart = m & ~31;
  for (int l0 = lstart; l0 < NL; l0 += 32) {
    *(h8*)&As[lr * 66 + c8]  = *(const h8*)(Qre + (size_t)(l0 + lr) * RTOT + (size_t)m * 64 + c8);
    *(h8*)&Ais[lr * 66 + c8] = *(const h8*)(Qim + (size_t)(l0 + lr) * RTOT + (size_t)m * 64 + c8);
    const float* pb = Bb + (size_t)(l0 + lr) * NLAT + k0b + c8;
    {
      float4 v0 = *(const float4*)pb;
      float4 v1 = *(const float4*)(pb + 4);
      h8 hb = {(f16)v0.x, (f16)v0.y, (f16)v0.z, (f16)v0.w,
               (f16)v1.x, (f16)v1.y, (f16)v1.z, (f16)v1.w};
      *(h8*)&Bs0[lr * 66 + c8] = hb;
    }
    {
      float4 v0 = *(const float4*)(pb + 64);
      float4 v1 = *(const float4*)(pb + 68);
      h8 hb = {(f16)v0.x, (f16)v0.y, (f16)v0.z, (f16)v0.w,
               (f16)v1.x, (f16)v1.y, (f16)v1.z, (f16)v1.w};
      *(h8*)&Bs1[lr * 66 + c8] = hb;
    }
    __syncthreads();
    h8 a0, a1, c0, c1, b0, b1, b2, b3;
#pragma unroll
    for (int e = 0; e < 8; ++e) {
      int row = (kg + e) * 66;
      a0[e] = As[row + wm + fr];
      a1[e] = As[row + wm + 16 + fr];
      c0[e] = Ais[row + wm + fr];
      c1[e] = Ais[row + wm + 16 + fr];
      b0[e] = Bs0[row + wn + fr];
      b1[e] = Bs0[row + wn + 16 + fr];
      b2[e] = Bs1[row + wn + fr];
      b3[e] = Bs1[row + wn + 16 + fr];
    }
    aR[0][0] = mfma16(a0, b0, aR[0][0]); aR[0][1] = mfma16(a0, b1, aR[0][1]);
    aR[0][2] = mfma16(a0, b2, aR[0][2]); aR[0][3] = mfma16(a0, b3, aR[0][3]);
    aR[1][0] = mfma16(a1, b0, aR[1][0]); aR[1][1] = mfma16(a1, b1, aR[1][1]);
    aR[1][2] = mfma16(a1, b2, aR[1][2]); aR[1][3] = mfma16(a1, b3, aR[1][3]);
    aI[0][0] = mfma16(c0, b0, aI[0][0]); aI[0][1] = mfma16(c0, b1, aI[0][1]);
    aI[0][2] = mfma16(c0, b2, aI[0][2]); aI[0][3] = mfma16(c0, b3, aI[0][3]);
    aI[1][0] = mfma16(c1, b0, aI[1][0]); aI[1][1] = mfma16(c1, b1, aI[1][1]);
    aI[1][2] = mfma16(c1, b2, aI[1][2]); aI[1][3] = mfma16(c1, b3, aI[1][3]);
    __syncthreads();
  }
  int drow = (lane >> 4) * 4, dcol = lane & 15;
#pragma unroll
  for (int i = 0; i < 2; ++i)
#pragma unroll
    for (int j = 0; j < 4; ++j)
#pragma unroll
      for (int b = 0; b < 4; ++b) {
        int orow = wm + i * 16 + drow + b;
        int kcol = k0b + (j >> 1) * 64 + (j & 1) * 16 + wn + dcol;
        size_t o = (size_t)m * RTOT + (size_t)orow * NLAT + kcol;
        XKre[o] = (f16)aR[i][j][b];
        XKim[o] = (f16)aI[i][j][b];
      }
}

// ---- S5: y[r][n] = sum_m XK[m][r]*Gr[n][m] + XKim[m][r]*Gi[n][m]; n-tile 128 ----
__global__ __launch_bounds__(256) void k_s5(
    const f16* __restrict__ XKre, const f16* __restrict__ XKim,
    const f16* __restrict__ Gr, const f16* __restrict__ Gi,
    float* __restrict__ y) {
  __shared__ f16 Ar[32 * 66], Ai[32 * 66], Br[128 * 34], Bi[128 * 34];
  int t = threadIdx.x;
  int n0 = blockIdx.x * 128, r0 = blockIdx.y * 64;
  int lane = t & 63, w = t >> 6;
  int wm = (w >> 1) * 32, wn = (w & 1) * 32;
  int fr = lane & 15, kg = (lane >> 4) * 8;
  int mr = t >> 3, r8 = (t & 7) * 8;
  f4 acc[2][4] = {};
  for (int m0 = 0; m0 < NM; m0 += 32) {
    *(h8*)&Ar[mr * 66 + r8] = *(const h8*)(XKre + (size_t)(m0 + mr) * RTOT + r0 + r8);
    *(h8*)&Ai[mr * 66 + r8] = *(const h8*)(XKim + (size_t)(m0 + mr) * RTOT + r0 + r8);
#pragma unroll
    for (int rep = 0; rep < 2; ++rep) {
      int f = rep * 256 + t;
      int row = f >> 2, cc = (f & 3) * 8;
      *(h8*)&Br[row * 34 + cc] = *(const h8*)(Gr + (size_t)(n0 + row) * NM + m0 + cc);
      *(h8*)&Bi[row * 34 + cc] = *(const h8*)(Gi + (size_t)(n0 + row) * NM + m0 + cc);
    }
    __syncthreads();
    h8 a0, a1, c0, c1;
#pragma unroll
    for (int e = 0; e < 8; ++e) {
      int row = (kg + e) * 66;
      a0[e] = Ar[row + wm + fr];
      a1[e] = Ar[row + wm + 16 + fr];
      c0[e] = Ai[row + wm + fr];
      c1[e] = Ai[row + wm + 16 + fr];
    }
#pragma unroll
    for (int j = 0; j < 4; ++j) {
      int nb = wn + (j & 1) * 16 + (j >> 1) * 64;
      h8 b = *(h8*)&Br[(nb + fr) * 34 + kg];
      h8 d = *(h8*)&Bi[(nb + fr) * 34 + kg];
      acc[0][j] = mfma16(a0, b, acc[0][j]);
      acc[1][j] = mfma16(a1, b, acc[1][j]);
      acc[0][j] = mfma16(c0, d, acc[0][j]);
      acc[1][j] = mfma16(c1, d, acc[1][j]);
    }
    __syncthreads();
  }
  int drow = (lane >> 4) * 4, dcol = lane & 15;
#pragma unroll
  for (int i = 0; i < 2; ++i)
#pragma unroll
    for (int j = 0; j < 4; ++j)
#pragma unroll
      for (int b = 0; b < 4; ++b) {
        int rg = r0 + wm + i * 16 + drow + b;
        int ng = n0 + wn + (j & 1) * 16 + (j >> 1) * 64 + dcol;
        y[(size_t)rg * NLON + ng] = acc[i][j][b];
      }
}

extern "C" void kernel_launch(void* const* d_in, const int* in_sizes, int n_in,
                              void* d_out, int out_size, void* d_ws, size_t ws_size,
                              hipStream_t stream) {
  const float* x    = (const float*)d_in[0];
  const float* wgr  = (const float*)d_in[1];
  const float* wgi  = (const float*)d_in[2];
  const float* pct  = (const float*)d_in[3];
  const float* shtw = (const float*)d_in[4];
  float* out = (float*)d_out;
  char* ws = (char*)d_ws;

  f16* Ftr = (f16*)(ws + BO_FTR);
  f16* Fti = (f16*)(ws + BO_FTI);
  f16* Gr  = (f16*)(ws + BO_GR);
  f16* Gi  = (f16*)(ws + BO_GI);
  f16* wTr = (f16*)(ws + BO_WTR);
  f16* wTi = (f16*)(ws + BO_WTI);
  f16* XFre = (f16*)(ws + BO_XFRE);  // XF, later XK
  f16* XFim = (f16*)(ws + BO_XFIM);
  f16* Pre  = (f16*)(ws + BO_PRE);
  f16* Pim  = (f16*)(ws + BO_PIM);
  f16* Qre  = (f16*)(ws + BO_QRE);
  f16* Qim  = (f16*)(ws + BO_QIM);

  float* res = out + (size_t)NC * NLAT * NLON;

  hipLaunchKernelGGL(k_tables_h, dim3(512), dim3(256), 0, stream, Ftr, Fti, Gr, Gi);
  hipLaunchKernelGGL(k_permw2, dim3(8, 2, 128), dim3(32, 8), 0, stream, wgr, wgi, wTr, wTi);
  // S1: forward DFT -> XF[m][c][k], fused residual
  hipLaunchKernelGGL(k_s1, dim3(2, 256), dim3(256), 0, stream, x, Ftr, Fti, XFre, XFim, res);
  // S2: forward Legendre -> P[l][m][c]
  hipLaunchKernelGGL(k_s2, dim3(4, 256), dim3(256), 0, stream, XFre, XFim, shtw, Pre, Pim);
  // S3: per-l weight GEMM -> Q[l][m][o]
  hipLaunchKernelGGL(k_s3, dim3(4, 256), dim3(256), 0, stream, Pre, Pim, wTr, wTi, Qre, Qim);
  // S4: inverse Legendre -> XK[m][o][k] (into XF region)
  hipLaunchKernelGGL(k_s4, dim3(2, 256), dim3(256), 0, stream, Qre, Qim, pct, XFre, XFim);
  // S5: inverse DFT -> y
  hipLaunchKernelGGL(k_s5, dim3(4, 256), dim3(256), 0, stream, XFre, XFim, Gr, Gi, out);
}